// Round 12
// baseline (277.131 us; speedup 1.0000x reference)
//
#include <hip/hip_runtime.h>

#define MUL 128

typedef __attribute__((ext_vector_type(8))) short bf16x8;
typedef __attribute__((ext_vector_type(4))) short bf16x4;
typedef __attribute__((ext_vector_type(4))) float f32x4;

__device__ __constant__ float kINV_UP   = 0.08838834764831845f;  // 1/sqrt(128)
__device__ __constant__ float kINV_L1   = 0.35355339059327373f;  // 1/sqrt(8)
__device__ __constant__ float kINV_L2   = 0.125f;                // 1/sqrt(64)
__device__ __constant__ float kINV_L3   = 0.125f;
__device__ __constant__ float kINV_LIN  = 0.00390625f;           // 1/(sqrt(256)*16)
__device__ __constant__ float kINV_SK   = 0.044194173824159216f; // 1/sqrt(512)
__device__ __constant__ float kINV_SQ3  = 0.5773502691896258f;   // 1/sqrt(3)

// intra-wave LDS ordering: drain ds ops; memory clobber keeps ds_reads below.
#define WAVE_LDS_SYNC() asm volatile("s_waitcnt lgkmcnt(0)" ::: "memory")

static __device__ __forceinline__ short f2bf(float f) {
  unsigned u = __float_as_uint(f);
  unsigned r = (u + 0x7FFFu + ((u >> 16) & 1u)) >> 16;  // RNE
  return (short)r;
}

// ---------------------------------------------------------------------------
// K1 (fused): weight conversion (blocks [0,CVT_B)) | receiver count (rest).
// ---------------------------------------------------------------------------
__global__ __launch_bounds__(256) void k_cvtcnt(
    const float* __restrict__ W_up0, const float* __restrict__ W_up1,
    const float* __restrict__ W_lin0, const float* __restrict__ W_lin1,
    const float* __restrict__ W_sk0, const float* __restrict__ W_sk1,
    const float* __restrict__ W_mlp2, const float* __restrict__ W_mlp3,
    short* __restrict__ W0T, short* __restrict__ W1T,
    short* __restrict__ Wl0T, short* __restrict__ Wl1T,
    short* __restrict__ Wsk0T, short* __restrict__ Wsk1T,
    short* __restrict__ W2T, short* __restrict__ W3T,
    const int* __restrict__ eidx, int* __restrict__ cnt, int E, int CVT_B) {
  int blk = blockIdx.x;
  if (blk >= CVT_B) {
    int e = (blk - CVT_B) * 256 + threadIdx.x;
    if (e < E) atomicAdd(&cnt[eidx[E + e]], 1);
    return;
  }
  int id = blk * 256 + threadIdx.x;
  if (id < 16384) {
    int w = id >> 7, u = id & 127;
    W0T[id] = f2bf(W_up0[u * 128 + w]);
    return;
  }
  id -= 16384;
  if (id < 16384) {
    int w = id >> 7, u = id & 127;
    W1T[id] = f2bf(W_up1[u * 128 + w]);
    return;
  }
  id -= 16384;
  if (id < 32768) {
    int w = id >> 8, u = id & 255;
    Wl0T[id] = f2bf(W_lin0[u * 128 + w]);
    return;
  }
  id -= 32768;
  if (id < 32768) {
    int w = id >> 8, u = id & 255;
    Wl1T[id] = f2bf(W_lin1[u * 128 + w]);
    return;
  }
  id -= 32768;
  if (id < 65536) {
    int w = id >> 9, k = id & 511;
    int v = k >> 7, u = k & 127;
    Wsk0T[id] = f2bf(W_sk0[(u * 4 + v) * 128 + w]);
    return;
  }
  id -= 65536;
  if (id < 65536) {
    int w = id >> 9, k = id & 511;
    int v = k >> 7, u = k & 127;
    Wsk1T[id] = f2bf(W_sk1[(u * 4 + v) * 128 + w]);
    return;
  }
  id -= 65536;
  if (id < 4096) {
    int c = id >> 6, k = id & 63;
    W2T[id] = f2bf(W_mlp2[k * 64 + c]);
    return;
  }
  id -= 4096;
  if (id < 32768) {
    int c = id >> 6, k = id & 63;
    W3T[id] = f2bf(W_mlp3[k * 512 + c]);
  }
}

// ---------------------------------------------------------------------------
// K2: exclusive scan over counts (1 block).
// ---------------------------------------------------------------------------
__global__ __launch_bounds__(1024) void k_scan(const int* __restrict__ cnt,
                                               int* __restrict__ offs,
                                               int* __restrict__ cursor, int N) {
  __shared__ int part[1024];
  const int t = threadIdx.x;
  int CH = (N + 1023) >> 10;
  if (CH > 16) CH = 16;
  const int base = t * CH;
  int loc[16];
  int s = 0;
  for (int i = 0; i < CH; ++i) {
    int idx = base + i;
    loc[i] = (idx < N) ? cnt[idx] : 0;
    s += loc[i];
  }
  part[t] = s;
  __syncthreads();
  for (int off = 1; off < 1024; off <<= 1) {
    int v = part[t];
    int add = (t >= off) ? part[t - off] : 0;
    __syncthreads();
    part[t] = v + add;
    __syncthreads();
  }
  int excl = part[t] - s;
  for (int i = 0; i < CH; ++i) {
    int idx = base + i;
    if (idx < N) { offs[idx] = excl; cursor[idx] = excl; }
    excl += loc[i];
  }
  if (t == 1023) offs[N] = part[1023];
}

// ---------------------------------------------------------------------------
// K3: scatter (standalone so recs exists before the MLP runs):
//     recs[p] = {eid, sender}, p = sorted-by-receiver position.
// ---------------------------------------------------------------------------
__global__ __launch_bounds__(256) void k_scatter(
    const int* __restrict__ eidx, int* __restrict__ cursor,
    uint2* __restrict__ recs, int E) {
  int e = blockIdx.x * 256 + threadIdx.x;
  if (e < E) {
    int r = eidx[E + e];
    int snd = eidx[e];
    int p = atomicAdd(&cursor[r], 1);
    recs[p] = make_uint2((unsigned)e, (unsigned)snd);
  }
}

// ---------------------------------------------------------------------------
// K4 (fused, block-range dispatch):
//   [0, MLP_B)   : per-edge MLP BY SORTED POSITION -> tpw2[p]. 128 pos/block,
//                  32 pos/WAVE (2 MFMA B-sets), sw-pipelined layer-3.
//                  eid from recs[p] (ef reads random 32B, L2-resident).
//   [MLP_B, ...) : node up-projection (MFMA, unchanged).
// ---------------------------------------------------------------------------
__global__ __launch_bounds__(256) void k_mlpup(
    const uint2* __restrict__ recs,
    const float* __restrict__ nf, const short* __restrict__ W0T,
    const short* __restrict__ W1T, float* __restrict__ s_up, float* __restrict__ v_up,
    const float* __restrict__ ef, const float* __restrict__ W1f,
    const short* __restrict__ W2T, const short* __restrict__ W3T,
    unsigned* __restrict__ tpw2, int N, int E, int MLP_B) {
  __shared__ __align__(16) char smem[48128];
  const int t = threadIdx.x;
  int blk = blockIdx.x;

  if (blk < MLP_B) {
    // ---------------- MLP role: 128 positions/block, 32 per wave -----------
    float* sW1  = (float*)smem;
    short* sW2T = (short*)(smem + 2048);
    short* sh1  = (short*)(smem + 11264);
    short* sh2  = (short*)(smem + 29696);

    for (int i = t * 4; i < 512; i += 1024)
      *reinterpret_cast<float4*>(&sW1[i]) = *reinterpret_cast<const float4*>(W1f + i);
    for (int i = t * 8; i < 4096; i += 2048) {
      int r = i >> 6, c = i & 63;
      *reinterpret_cast<bf16x8*>(&sW2T[r * 72 + c]) =
          *reinterpret_cast<const bf16x8*>(&W2T[r * 64 + c]);
    }
    __syncthreads();  // weights visible; no more block barriers

    const int w = t >> 6, l = t & 63, li = l & 15, g = l >> 4;
    const int pb = blk * 128 + w * 32;
    const int ps0 = pb + li, ps1 = pb + 16 + li;
    const bool ok0 = ps0 < E, ok1 = ps1 < E;
    const int eid0 = ok0 ? (int)recs[ps0].x : 0;
    const int eid1 = ok1 ? (int)recs[ps1].x : 0;
    short* h1r0 = sh1 + (w * 32 + li) * 72;
    short* h1r1 = sh1 + (w * 32 + 16 + li) * 72;
    short* h2r0 = sh2 + (w * 32 + li) * 72;
    short* h2r1 = sh2 + (w * 32 + 16 + li) * 72;

    // layer 1
    {
#pragma unroll
      for (int s = 0; s < 2; ++s) {
        const bool ok = s ? ok1 : ok0;
        const int eid = s ? eid1 : eid0;
        short* h1row = s ? h1r1 : h1r0;
        float4 qa = {0.f, 0.f, 0.f, 0.f}, qb = {0.f, 0.f, 0.f, 0.f};
        if (ok) {
          qa = *reinterpret_cast<const float4*>(ef + (size_t)eid * 8);
          qb = *reinterpret_cast<const float4*>(ef + (size_t)eid * 8 + 4);
        }
        const float x[8] = {qa.x, qa.y, qa.z, qa.w, qb.x, qb.y, qb.z, qb.w};
        bf16x8 p0, p1;
#pragma unroll
        for (int j = 0; j < 16; ++j) {
          int col = g * 16 + j;
          float a = 0.f;
#pragma unroll
          for (int k = 0; k < 8; ++k) a += x[k] * sW1[k * 64 + col];
          a *= kINV_L1;
          short hv = f2bf(a / (1.f + __expf(-a)));
          if (j < 8) p0[j] = hv; else p1[j - 8] = hv;
        }
        *reinterpret_cast<bf16x8*>(&h1row[g * 16])     = p0;
        *reinterpret_cast<bf16x8*>(&h1row[g * 16 + 8]) = p1;
      }
    }
    WAVE_LDS_SYNC();

    // layer 2 (MFMA, swapped)
    {
      bf16x8 hb0[2], hb1[2];
      hb0[0] = *reinterpret_cast<const bf16x8*>(&h1r0[g * 8]);
      hb1[0] = *reinterpret_cast<const bf16x8*>(&h1r0[32 + g * 8]);
      hb0[1] = *reinterpret_cast<const bf16x8*>(&h1r1[g * 8]);
      hb1[1] = *reinterpret_cast<const bf16x8*>(&h1r1[32 + g * 8]);
#pragma unroll
      for (int ct = 0; ct < 4; ++ct) {
        const short* wrow = &sW2T[(ct * 16 + li) * 72];
        bf16x8 a0 = *reinterpret_cast<const bf16x8*>(&wrow[g * 8]);
        bf16x8 a1 = *reinterpret_cast<const bf16x8*>(&wrow[32 + g * 8]);
#pragma unroll
        for (int s = 0; s < 2; ++s) {
          f32x4 acc = {0.f, 0.f, 0.f, 0.f};
          acc = __builtin_amdgcn_mfma_f32_16x16x32_bf16(a0, hb0[s], acc, 0, 0, 0);
          acc = __builtin_amdgcn_mfma_f32_16x16x32_bf16(a1, hb1[s], acc, 0, 0, 0);
          bf16x4 hq;
#pragma unroll
          for (int r = 0; r < 4; ++r) {
            float a = acc[r] * kINV_L2;
            hq[r] = f2bf(a / (1.f + __expf(-a)));
          }
          *reinterpret_cast<bf16x4*>(&((s ? h2r1 : h2r0)[ct * 16 + g * 4])) = hq;
        }
      }
    }
    WAVE_LDS_SYNC();

    // layer 3 (MFMA, swapped, 2-deep software pipeline on W3T A-fragments)
    {
      bf16x8 b0[2], b1[2];
      b0[0] = *reinterpret_cast<const bf16x8*>(&h2r0[g * 8]);
      b1[0] = *reinterpret_cast<const bf16x8*>(&h2r0[32 + g * 8]);
      b0[1] = *reinterpret_cast<const bf16x8*>(&h2r1[g * 8]);
      b1[1] = *reinterpret_cast<const bf16x8*>(&h2r1[32 + g * 8]);

      bf16x8 c0, c1, c2, c3;
      {
        const int rowA = li;
        c0 = *reinterpret_cast<const bf16x8*>(&W3T[(size_t)rowA * 64 + g * 8]);
        c1 = *reinterpret_cast<const bf16x8*>(&W3T[(size_t)rowA * 64 + 32 + g * 8]);
        c2 = *reinterpret_cast<const bf16x8*>(&W3T[(size_t)(rowA + 256) * 64 + g * 8]);
        c3 = *reinterpret_cast<const bf16x8*>(&W3T[(size_t)(rowA + 256) * 64 + 32 + g * 8]);
      }
#pragma unroll
      for (int rt = 0; rt < 16; ++rt) {
        bf16x8 n0, n1, n2, n3;
        const bool pf = (rt < 15);
        if (pf) {
          const int rowA = (rt + 1) * 16 + li;
          n0 = *reinterpret_cast<const bf16x8*>(&W3T[(size_t)rowA * 64 + g * 8]);
          n1 = *reinterpret_cast<const bf16x8*>(&W3T[(size_t)rowA * 64 + 32 + g * 8]);
          n2 = *reinterpret_cast<const bf16x8*>(&W3T[(size_t)(rowA + 256) * 64 + g * 8]);
          n3 = *reinterpret_cast<const bf16x8*>(&W3T[(size_t)(rowA + 256) * 64 + 32 + g * 8]);
        }
#pragma unroll
        for (int s = 0; s < 2; ++s) {
          f32x4 accA = {0.f, 0.f, 0.f, 0.f};
          f32x4 accB = {0.f, 0.f, 0.f, 0.f};
          accA = __builtin_amdgcn_mfma_f32_16x16x32_bf16(c0, b0[s], accA, 0, 0, 0);
          accA = __builtin_amdgcn_mfma_f32_16x16x32_bf16(c1, b1[s], accA, 0, 0, 0);
          accB = __builtin_amdgcn_mfma_f32_16x16x32_bf16(c2, b0[s], accB, 0, 0, 0);
          accB = __builtin_amdgcn_mfma_f32_16x16x32_bf16(c3, b1[s], accB, 0, 0, 0);
          if (s ? ok1 : ok0) {
            uint4 d;
            unsigned* dp = &d.x;
#pragma unroll
            for (int r = 0; r < 4; ++r) {
              unsigned lo = (unsigned)(unsigned short)f2bf(accA[r] * kINV_L3);
              unsigned hi = (unsigned)(unsigned short)f2bf(accB[r] * kINV_L3);
              dp[r] = lo | (hi << 16);
            }
            *reinterpret_cast<uint4*>(
                &tpw2[(size_t)(s ? ps1 : ps0) * 256 + rt * 16 + g * 4]) = d;
          }
        }
        if (pf) { c0 = n0; c1 = n1; c2 = n2; c3 = n3; }
      }
    }
    return;
  }
  blk -= MLP_B;

  // ---------------- UP role: node up-projection (MFMA) ---------------------
  {
    short* lsA = (short*)smem;  // [4][16][136]
    const int nb = blk * 16;

    for (int base = t * 8; base < 16 * 512; base += 256 * 8) {
      int n = base >> 9, j0 = base & 511;
      float vals[8];
      if (nb + n < N) {
        float4 q0 = *reinterpret_cast<const float4*>(nf + (size_t)(nb + n) * 512 + j0);
        float4 q1 = *reinterpret_cast<const float4*>(nf + (size_t)(nb + n) * 512 + j0 + 4);
        vals[0] = q0.x; vals[1] = q0.y; vals[2] = q0.z; vals[3] = q0.w;
        vals[4] = q1.x; vals[5] = q1.y; vals[6] = q1.z; vals[7] = q1.w;
      } else {
#pragma unroll
        for (int e = 0; e < 8; ++e) vals[e] = 0.f;
      }
#pragma unroll
      for (int e = 0; e < 8; ++e) {
        int idx = j0 + e;
        if (idx < 128) {
          lsA[(0 * 16 + n) * 136 + idx] = f2bf(vals[e]);
        } else {
          unsigned q = idx - 128;
          unsigned u = q / 3u;
          unsigned i = q - u * 3u;
          lsA[((1 + i) * 16 + n) * 136 + u] = f2bf(vals[e]);
        }
      }
    }
    __syncthreads();

    const int c = t >> 6;
    const int lane = t & 63;
    const int col = lane & 15;
    const int g = lane >> 4;

    const short* WT = c ? W1T : W0T;

    bf16x8 af[4];
#pragma unroll
    for (int kk = 0; kk < 4; ++kk)
      af[kk] = *reinterpret_cast<const bf16x8*>(&lsA[(c * 16 + col) * 136 + kk * 32 + g * 8]);

#pragma unroll
    for (int nt = 0; nt < 8; ++nt) {
      f32x4 acc = {0.f, 0.f, 0.f, 0.f};
#pragma unroll
      for (int kk = 0; kk < 4; ++kk) {
        bf16x8 bf = *reinterpret_cast<const bf16x8*>(&WT[(size_t)(nt * 16 + col) * 128 + kk * 32 + g * 8]);
        acc = __builtin_amdgcn_mfma_f32_16x16x32_bf16(af[kk], bf, acc, 0, 0, 0);
      }
#pragma unroll
      for (int r = 0; r < 4; ++r) {
        int nd = nb + g * 4 + r;
        if (nd < N) {
          float val = acc[r] * kINV_UP;
          if (c == 0) s_up[(size_t)nd * 128 + nt * 16 + col] = val;
          else        v_up[(size_t)nd * 384 + (c - 1) * 128 + nt * 16 + col] = val;
        }
      }
    }
  }
}

// ---------------------------------------------------------------------------
// K5: gather, one WAVE per node, BOTH sides, CHUNK-OF-4. tpw2 and recs are
// POSITION-indexed -> pure sequential streams; only eattr (16B) and node
// rows (L2/L3-resident) are random. Tail masked by zeroing ea.
// ---------------------------------------------------------------------------
__global__ __launch_bounds__(256) void k_gather(
    const uint2* __restrict__ recs, const int* __restrict__ offs,
    const unsigned* __restrict__ tpw2, const float* __restrict__ eattr,
    const float* __restrict__ s_up, const float* __restrict__ v_up,
    float* __restrict__ Ms, float* __restrict__ Mv, int N) {
  const int t = threadIdx.x;
  const int n = blockIdx.x * 4 + (t >> 6);
  if (n >= N) return;
  const int l = t & 63;
  const int u0 = l * 2;

  float aMsS0 = 0.f, aMsS1 = 0.f;   // m0 -> Ms[0:128)
  float aMsV0 = 0.f, aMsV1 = 0.f;   // m1 -> Ms[128:256)
  float aVs[3][2] = {};             // m2 -> Mv[i][0:128)
  float aVv[3][2] = {};             // m3 -> Mv[i][128:256)

  const int e0 = offs[n], e1 = offs[n + 1];
  const int last = e1 - 1;

  for (int p0 = e0; p0 < e1; p0 += 4) {
    const int p1 = min(p0 + 1, last);
    const int p2 = min(p0 + 2, last);
    const int p3 = min(p0 + 3, last);
    // chunk records (broadcast loads)
    uint2 rc0 = recs[p0];
    uint2 rc1 = recs[p1];
    uint2 rc2 = recs[p2];
    uint2 rc3 = recs[p3];

    // issue ALL chunk loads (independent); tpw2 now sequential by position
    float4 ea0 = *reinterpret_cast<const float4*>(eattr + (size_t)rc0.x * 4);
    float4 ea1 = *reinterpret_cast<const float4*>(eattr + (size_t)rc1.x * 4);
    float4 ea2 = *reinterpret_cast<const float4*>(eattr + (size_t)rc2.x * 4);
    float4 ea3 = *reinterpret_cast<const float4*>(eattr + (size_t)rc3.x * 4);
    uint2 qs0 = *reinterpret_cast<const uint2*>(tpw2 + (size_t)p0 * 256 + u0);
    uint2 qs1 = *reinterpret_cast<const uint2*>(tpw2 + (size_t)p1 * 256 + u0);
    uint2 qs2 = *reinterpret_cast<const uint2*>(tpw2 + (size_t)p2 * 256 + u0);
    uint2 qs3 = *reinterpret_cast<const uint2*>(tpw2 + (size_t)p3 * 256 + u0);
    uint2 qv0 = *reinterpret_cast<const uint2*>(tpw2 + (size_t)p0 * 256 + 128 + u0);
    uint2 qv1 = *reinterpret_cast<const uint2*>(tpw2 + (size_t)p1 * 256 + 128 + u0);
    uint2 qv2 = *reinterpret_cast<const uint2*>(tpw2 + (size_t)p2 * 256 + 128 + u0);
    uint2 qv3 = *reinterpret_cast<const uint2*>(tpw2 + (size_t)p3 * 256 + 128 + u0);
    float2 xs0 = *reinterpret_cast<const float2*>(s_up + (size_t)rc0.y * 128 + u0);
    float2 xs1 = *reinterpret_cast<const float2*>(s_up + (size_t)rc1.y * 128 + u0);
    float2 xs2 = *reinterpret_cast<const float2*>(s_up + (size_t)rc2.y * 128 + u0);
    float2 xs3 = *reinterpret_cast<const float2*>(s_up + (size_t)rc3.y * 128 + u0);
    const float* xvp0 = v_up + (size_t)rc0.y * 384 + u0;
    const float* xvp1 = v_up + (size_t)rc1.y * 384 + u0;
    const float* xvp2 = v_up + (size_t)rc2.y * 384 + u0;
    const float* xvp3 = v_up + (size_t)rc3.y * 384 + u0;
    float2 xa0 = *reinterpret_cast<const float2*>(xvp0);
    float2 xb0 = *reinterpret_cast<const float2*>(xvp0 + 128);
    float2 xc0 = *reinterpret_cast<const float2*>(xvp0 + 256);
    float2 xa1 = *reinterpret_cast<const float2*>(xvp1);
    float2 xb1 = *reinterpret_cast<const float2*>(xvp1 + 128);
    float2 xc1 = *reinterpret_cast<const float2*>(xvp1 + 256);
    float2 xa2 = *reinterpret_cast<const float2*>(xvp2);
    float2 xb2 = *reinterpret_cast<const float2*>(xvp2 + 128);
    float2 xc2 = *reinterpret_cast<const float2*>(xvp2 + 256);
    float2 xa3 = *reinterpret_cast<const float2*>(xvp3);
    float2 xb3 = *reinterpret_cast<const float2*>(xvp3 + 128);
    float2 xc3 = *reinterpret_cast<const float2*>(xvp3 + 256);

    // tail mask via ea (all message terms factor through an ea component)
    const int m = e1 - p0;
    if (m < 4) {
      float k1 = (m > 1) ? 1.f : 0.f;
      float k2 = (m > 2) ? 1.f : 0.f;
      ea1.x *= k1; ea1.y *= k1; ea1.z *= k1; ea1.w *= k1;
      ea2.x *= k2; ea2.y *= k2; ea2.z *= k2; ea2.w *= k2;
      ea3.x = 0.f; ea3.y = 0.f; ea3.z = 0.f; ea3.w = 0.f;
    }

#define ACC_EDGE(EA, QS, QV, XS, XA, XB, XC)                                   \
    {                                                                          \
      float tA0 = __uint_as_float(QS.x << 16);                                 \
      float tB0 = __uint_as_float(QS.x & 0xFFFF0000u);                         \
      float tA1 = __uint_as_float(QS.y << 16);                                 \
      float tB1 = __uint_as_float(QS.y & 0xFFFF0000u);                         \
      aMsS0 += tA0 * XS.x * EA.x;                                              \
      aMsS1 += tA1 * XS.y * EA.x;                                              \
      float wc0 = tB0 * XS.x, wc1 = tB1 * XS.y;                                \
      aVs[0][0] += wc0 * EA.y; aVs[0][1] += wc1 * EA.y;                        \
      aVs[1][0] += wc0 * EA.z; aVs[1][1] += wc1 * EA.z;                        \
      aVs[2][0] += wc0 * EA.w; aVs[2][1] += wc1 * EA.w;                        \
      float uA0 = __uint_as_float(QV.x << 16);                                 \
      float uB0 = __uint_as_float(QV.x & 0xFFFF0000u);                         \
      float uA1 = __uint_as_float(QV.y << 16);                                 \
      float uB1 = __uint_as_float(QV.y & 0xFFFF0000u);                         \
      float dot0 = XA.x * EA.y + XB.x * EA.z + XC.x * EA.w;                    \
      float dot1 = XA.y * EA.y + XB.y * EA.z + XC.y * EA.w;                    \
      aMsV0 += uA0 * dot0 * kINV_SQ3;                                          \
      aMsV1 += uA1 * dot1 * kINV_SQ3;                                          \
      float wd0 = uB0 * EA.x, wd1 = uB1 * EA.x;                                \
      aVv[0][0] += wd0 * XA.x; aVv[0][1] += wd1 * XA.y;                        \
      aVv[1][0] += wd0 * XB.x; aVv[1][1] += wd1 * XB.y;                        \
      aVv[2][0] += wd0 * XC.x; aVv[2][1] += wd1 * XC.y;                        \
    }

    ACC_EDGE(ea0, qs0, qv0, xs0, xa0, xb0, xc0)
    ACC_EDGE(ea1, qs1, qv1, xs1, xa1, xb1, xc1)
    ACC_EDGE(ea2, qs2, qv2, xs2, xa2, xb2, xc2)
    ACC_EDGE(ea3, qs3, qv3, xs3, xa3, xb3, xc3)
#undef ACC_EDGE
  }

  *reinterpret_cast<float2*>(Ms + (size_t)n * 256 + u0)       = make_float2(aMsS0, aMsS1);
  *reinterpret_cast<float2*>(Ms + (size_t)n * 256 + 128 + u0) = make_float2(aMsV0, aMsV1);
#pragma unroll
  for (int i = 0; i < 3; ++i) {
    *reinterpret_cast<float2*>(Mv + (size_t)n * 768 + i * 256 + u0) =
        make_float2(aVs[i][0], aVs[i][1]);
    *reinterpret_cast<float2*>(Mv + (size_t)n * 768 + i * 256 + 128 + u0) =
        make_float2(aVv[i][0], aVv[i][1]);
  }
}

// ---------------------------------------------------------------------------
// K6 (MFMA): fused lin + skip + combine (unchanged — passed).
// ---------------------------------------------------------------------------
__global__ __launch_bounds__(256) void k_linskip(
    const float* __restrict__ Ms, const float* __restrict__ Mv,
    const short* __restrict__ Wl0T, const short* __restrict__ Wl1T,
    const short* __restrict__ Wsk0T, const short* __restrict__ Wsk1T,
    const float* __restrict__ attrs, const float* __restrict__ upd,
    float* __restrict__ out, int N) {
  __shared__ __align__(16) short lsA[4][16][264];
  __shared__ __align__(16) short lsS[4][16][136];
  __shared__ float sat[16][4];
  const int nb = blockIdx.x * 16;
  const int t = threadIdx.x;

  for (int base = t * 4; base < 16 * 1024; base += 1024) {
    int n = base >> 10, j = base & 1023;
    int comp = j >> 8, u = j & 255;
    float4 q = {0.f, 0.f, 0.f, 0.f};
    if (nb + n < N) {
      const float* src = (comp == 0) ? (Ms + (size_t)(nb + n) * 256 + u)
                                     : (Mv + (size_t)(nb + n) * 768 + (size_t)(comp - 1) * 256 + u);
      q = *reinterpret_cast<const float4*>(src);
    }
    lsA[comp][n][u + 0] = f2bf(q.x);
    lsA[comp][n][u + 1] = f2bf(q.y);
    lsA[comp][n][u + 2] = f2bf(q.z);
    lsA[comp][n][u + 3] = f2bf(q.w);
  }
  if (t < 64) {
    int n = t >> 2, v = t & 3;
    sat[n][v] = (nb + n < N) ? attrs[(size_t)(nb + n) * 4 + v] : 0.f;
  }
  __syncthreads();

  const int c = t >> 6;
  const int lane = t & 63;
  const int col = lane & 15;
  const int g = lane >> 4;

  const short* WLT = c ? Wl1T : Wl0T;
  const short* WST = c ? Wsk1T : Wsk0T;

  bf16x8 af1[8];
#pragma unroll
  for (int kk = 0; kk < 8; ++kk)
    af1[kk] = *reinterpret_cast<const bf16x8*>(&lsA[c][col][kk * 32 + g * 8]);

  f32x4 Sreg[8];
#pragma unroll
  for (int nt = 0; nt < 8; ++nt) {
    f32x4 acc = {0.f, 0.f, 0.f, 0.f};
#pragma unroll
    for (int kk = 0; kk < 8; ++kk) {
      bf16x8 bf = *reinterpret_cast<const bf16x8*>(&WLT[(size_t)(nt * 16 + col) * 256 + kk * 32 + g * 8]);
      acc = __builtin_amdgcn_mfma_f32_16x16x32_bf16(af1[kk], bf, acc, 0, 0, 0);
    }
#pragma unroll
    for (int r = 0; r < 4; ++r) acc[r] *= kINV_LIN;
    Sreg[nt] = acc;
#pragma unroll
    for (int r = 0; r < 4; ++r)
      lsS[c][g * 4 + r][nt * 16 + col] = f2bf(acc[r]);
  }

  float satr[4][4];
#pragma unroll
  for (int r = 0; r < 4; ++r)
#pragma unroll
    for (int v = 0; v < 4; ++v) satr[r][v] = sat[g * 4 + r][v];

  __syncthreads();

  bf16x8 af2[4];
#pragma unroll
  for (int kk = 0; kk < 4; ++kk)
    af2[kk] = *reinterpret_cast<const bf16x8*>(&lsS[c][col][kk * 32 + g * 8]);

  const float p = upd[0];
  const float cc = 1.f / (1.f + __expf(-p));
  const float c_old = rsqrtf(cc * cc + 1.f);
  const float c_new = cc * c_old;

#pragma unroll
  for (int nt = 0; nt < 8; ++nt) {
    float fin[4] = {0.f, 0.f, 0.f, 0.f};
#pragma unroll
    for (int v = 0; v < 4; ++v) {
      f32x4 tmp = {0.f, 0.f, 0.f, 0.f};
#pragma unroll
      for (int kk = 0; kk < 4; ++kk) {
        bf16x8 bf = *reinterpret_cast<const bf16x8*>(&WST[(size_t)(nt * 16 + col) * 512 + v * 128 + kk * 32 + g * 8]);
        tmp = __builtin_amdgcn_mfma_f32_16x16x32_bf16(af2[kk], bf, tmp, 0, 0, 0);
      }
#pragma unroll
      for (int r = 0; r < 4; ++r) fin[r] += satr[r][v] * tmp[r];
    }
#pragma unroll
    for (int r = 0; r < 4; ++r) {
      int nd = nb + g * 4 + r;
      if (nd < N) {
        float val = c_old * Sreg[nt][r] + c_new * fin[r] * kINV_SK;
        out[((size_t)nd * 128 + nt * 16 + col) * 4 + c] = val;
      }
    }
  }
}

extern "C" void kernel_launch(void* const* d_in, const int* in_sizes, int n_in,
                              void* d_out, int out_size, void* d_ws, size_t ws_size,
                              hipStream_t stream) {
  const float* node_attrs = (const float*)d_in[0];
  const float* node_feats = (const float*)d_in[1];
  const float* edge_attrs = (const float*)d_in[2];
  const float* edge_feats = (const float*)d_in[3];
  const int*   edge_index = (const int*)d_in[4];
  const float* W_up0  = (const float*)d_in[5];
  const float* W_up1  = (const float*)d_in[6];
  const float* W_mlp1 = (const float*)d_in[7];
  const float* W_mlp2 = (const float*)d_in[8];
  const float* W_mlp3 = (const float*)d_in[9];
  const float* W_lin0 = (const float*)d_in[10];
  const float* W_lin1 = (const float*)d_in[11];
  const float* W_skip0 = (const float*)d_in[12];
  const float* W_skip1 = (const float*)d_in[13];
  const float* upd = (const float*)d_in[14];
  float* out = (float*)d_out;

  const int N = in_sizes[0] / 4;
  const int E = in_sizes[4] / 2;

  float* ws = (float*)d_ws;
  float* s_up = ws;                          // N*128
  float* v_up = s_up + (size_t)N * 128;      // N*384  [n][i][u]
  float* Ms   = v_up + (size_t)N * 384;      // N*256
  float* Mv   = Ms + (size_t)N * 256;        // N*768  [n][i][u]
  int* cnt    = (int*)(Mv + (size_t)N * 768); // N
  int* offs   = cnt + N;                      // N+1
  int* cursor = offs + N + 1;                 // N
  uint2* recs = (uint2*)((((uintptr_t)(cursor + N)) + 7) & ~(uintptr_t)7);  // E uint2

  short* wbase = (short*)((((uintptr_t)(recs + E)) + 15) & ~(uintptr_t)15);
  short* W0T   = wbase;            // 128*128
  short* W1T   = W0T + 16384;      // 128*128
  short* Wl0T  = W1T + 16384;      // 128*256
  short* Wl1T  = Wl0T + 32768;     // 128*256
  short* Wsk0T = Wl1T + 32768;     // 128*512
  short* Wsk1T = Wsk0T + 65536;    // 128*512
  short* W2T   = Wsk1T + 65536;    // 64*64
  short* W3T   = W2T + 4096;       // 512*64
  unsigned* tpw2 = (unsigned*)(W3T + 32768); // E*256 dwords

  const int CVT_B = (266240 + 255) / 256;      // 1040
  const int CNT_B = (E + 255) / 256;
  const int SC_B  = (E + 255) / 256;
  const int MLP_B = (E + 127) / 128;
  const int UP_B  = (N + 15) / 16;

  hipMemsetAsync(cnt, 0, (size_t)N * sizeof(int), stream);

  k_cvtcnt<<<CVT_B + CNT_B, 256, 0, stream>>>(
      W_up0, W_up1, W_lin0, W_lin1, W_skip0, W_skip1, W_mlp2, W_mlp3,
      W0T, W1T, Wl0T, Wl1T, Wsk0T, Wsk1T, W2T, W3T,
      edge_index, cnt, E, CVT_B);
  k_scan<<<1, 1024, 0, stream>>>(cnt, offs, cursor, N);
  k_scatter<<<SC_B, 256, 0, stream>>>(edge_index, cursor, recs, E);
  k_mlpup<<<MLP_B + UP_B, 256, 0, stream>>>(
      recs, node_feats, W0T, W1T, s_up, v_up,
      edge_feats, W_mlp1, W2T, W3T, tpw2, N, E, MLP_B);
  k_gather<<<(N + 3) / 4, 256, 0, stream>>>(recs, offs, tpw2, edge_attrs,
                                            s_up, v_up, Ms, Mv, N);
  k_linskip<<<(N + 15) / 16, 256, 0, stream>>>(Ms, Mv, Wl0T, Wl1T, Wsk0T, Wsk1T,
                                               node_attrs, upd, out, N);
}

// Round 13
// 275.925 us; speedup vs baseline: 1.0044x; 1.0044x over previous
//
#include <hip/hip_runtime.h>

#define MUL 128

typedef __attribute__((ext_vector_type(8))) short bf16x8;
typedef __attribute__((ext_vector_type(4))) short bf16x4;
typedef __attribute__((ext_vector_type(4))) float f32x4;

__device__ __constant__ float kINV_UP   = 0.08838834764831845f;  // 1/sqrt(128)
__device__ __constant__ float kINV_L1   = 0.35355339059327373f;  // 1/sqrt(8)
__device__ __constant__ float kINV_L2   = 0.125f;                // 1/sqrt(64)
__device__ __constant__ float kINV_L3   = 0.125f;
__device__ __constant__ float kINV_LIN  = 0.00390625f;           // 1/(sqrt(256)*16)
__device__ __constant__ float kINV_SK   = 0.044194173824159216f; // 1/sqrt(512)
__device__ __constant__ float kINV_SQ3  = 0.5773502691896258f;   // 1/sqrt(3)

// intra-wave LDS ordering: drain ds ops; memory clobber keeps ds_reads below.
#define WAVE_LDS_SYNC() asm volatile("s_waitcnt lgkmcnt(0)" ::: "memory")

static __device__ __forceinline__ short f2bf(float f) {
  unsigned u = __float_as_uint(f);
  unsigned r = (u + 0x7FFFu + ((u >> 16) & 1u)) >> 16;  // RNE
  return (short)r;
}

// ---------------------------------------------------------------------------
// K1 (fused): weight conversion (blocks [0,CVT_B)) | receiver count (rest).
// ---------------------------------------------------------------------------
__global__ __launch_bounds__(256) void k_cvtcnt(
    const float* __restrict__ W_up0, const float* __restrict__ W_up1,
    const float* __restrict__ W_lin0, const float* __restrict__ W_lin1,
    const float* __restrict__ W_sk0, const float* __restrict__ W_sk1,
    const float* __restrict__ W_mlp2, const float* __restrict__ W_mlp3,
    short* __restrict__ W0T, short* __restrict__ W1T,
    short* __restrict__ Wl0T, short* __restrict__ Wl1T,
    short* __restrict__ Wsk0T, short* __restrict__ Wsk1T,
    short* __restrict__ W2T, short* __restrict__ W3T,
    const int* __restrict__ eidx, int* __restrict__ cnt, int E, int CVT_B) {
  int blk = blockIdx.x;
  if (blk >= CVT_B) {
    int e = (blk - CVT_B) * 256 + threadIdx.x;
    if (e < E) atomicAdd(&cnt[eidx[E + e]], 1);
    return;
  }
  int id = blk * 256 + threadIdx.x;
  if (id < 16384) {
    int w = id >> 7, u = id & 127;
    W0T[id] = f2bf(W_up0[u * 128 + w]);
    return;
  }
  id -= 16384;
  if (id < 16384) {
    int w = id >> 7, u = id & 127;
    W1T[id] = f2bf(W_up1[u * 128 + w]);
    return;
  }
  id -= 16384;
  if (id < 32768) {
    int w = id >> 8, u = id & 255;
    Wl0T[id] = f2bf(W_lin0[u * 128 + w]);
    return;
  }
  id -= 32768;
  if (id < 32768) {
    int w = id >> 8, u = id & 255;
    Wl1T[id] = f2bf(W_lin1[u * 128 + w]);
    return;
  }
  id -= 32768;
  if (id < 65536) {
    int w = id >> 9, k = id & 511;
    int v = k >> 7, u = k & 127;
    Wsk0T[id] = f2bf(W_sk0[(u * 4 + v) * 128 + w]);
    return;
  }
  id -= 65536;
  if (id < 65536) {
    int w = id >> 9, k = id & 511;
    int v = k >> 7, u = k & 127;
    Wsk1T[id] = f2bf(W_sk1[(u * 4 + v) * 128 + w]);
    return;
  }
  id -= 65536;
  if (id < 4096) {
    int c = id >> 6, k = id & 63;
    W2T[id] = f2bf(W_mlp2[k * 64 + c]);
    return;
  }
  id -= 4096;
  if (id < 32768) {
    int c = id >> 6, k = id & 63;
    W3T[id] = f2bf(W_mlp3[k * 512 + c]);
  }
}

// ---------------------------------------------------------------------------
// K2: exclusive scan over counts (1 block).
// ---------------------------------------------------------------------------
__global__ __launch_bounds__(1024) void k_scan(const int* __restrict__ cnt,
                                               int* __restrict__ offs,
                                               int* __restrict__ cursor, int N) {
  __shared__ int part[1024];
  const int t = threadIdx.x;
  int CH = (N + 1023) >> 10;
  if (CH > 16) CH = 16;
  const int base = t * CH;
  int loc[16];
  int s = 0;
  for (int i = 0; i < CH; ++i) {
    int idx = base + i;
    loc[i] = (idx < N) ? cnt[idx] : 0;
    s += loc[i];
  }
  part[t] = s;
  __syncthreads();
  for (int off = 1; off < 1024; off <<= 1) {
    int v = part[t];
    int add = (t >= off) ? part[t - off] : 0;
    __syncthreads();
    part[t] = v + add;
    __syncthreads();
  }
  int excl = part[t] - s;
  for (int i = 0; i < CH; ++i) {
    int idx = base + i;
    if (idx < N) { offs[idx] = excl; cursor[idx] = excl; }
    excl += loc[i];
  }
  if (t == 1023) offs[N] = part[1023];
}

// ---------------------------------------------------------------------------
// K3 (fused, block-range dispatch):
//   [0, MLP_B)   : per-edge MLP with SCATTER-ON-WRITE: edge e (eid-ordered,
//                  sequential ef reads) claims p = atomicAdd(cursor[rcv]),
//                  writes recs[p] and tpw2[p] (scattered writes, no stalls).
//                  128 edges/block, 32/WAVE, sw-pipelined layer-3.
//   [MLP_B, ...) : node up-projection (MFMA, unchanged).
// ---------------------------------------------------------------------------
__global__ __launch_bounds__(256) void k_fused3(
    const int* __restrict__ eidx, int* __restrict__ cursor, uint2* __restrict__ recs,
    const float* __restrict__ nf, const short* __restrict__ W0T,
    const short* __restrict__ W1T, float* __restrict__ s_up, float* __restrict__ v_up,
    const float* __restrict__ ef, const float* __restrict__ W1f,
    const short* __restrict__ W2T, const short* __restrict__ W3T,
    unsigned* __restrict__ tpw2, int N, int E, int MLP_B) {
  __shared__ __align__(16) char smem[48640];
  const int t = threadIdx.x;
  int blk = blockIdx.x;

  if (blk < MLP_B) {
    // ---------------- MLP role: 128 edges/block, 32 edges per wave ---------
    float* sW1  = (float*)smem;
    short* sW2T = (short*)(smem + 2048);
    short* sh1  = (short*)(smem + 11264);
    short* sh2  = (short*)(smem + 29696);
    int*   spos = (int*)(smem + 48128);   // [128] claimed positions

    for (int i = t * 4; i < 512; i += 1024)
      *reinterpret_cast<float4*>(&sW1[i]) = *reinterpret_cast<const float4*>(W1f + i);
    for (int i = t * 8; i < 4096; i += 2048) {
      int r = i >> 6, c = i & 63;
      *reinterpret_cast<bf16x8*>(&sW2T[r * 72 + c]) =
          *reinterpret_cast<const bf16x8*>(&W2T[r * 64 + c]);
    }
    __syncthreads();  // weights visible; no more block barriers

    const int w = t >> 6, l = t & 63, li = l & 15, g = l >> 4;
    const int eb = blk * 128 + w * 32;
    const int es0 = eb + li, es1 = eb + 16 + li;
    const bool ok0 = es0 < E, ok1 = es1 < E;
    short* h1r0 = sh1 + (w * 32 + li) * 72;
    short* h1r1 = sh1 + (w * 32 + 16 + li) * 72;
    short* h2r0 = sh2 + (w * 32 + li) * 72;
    short* h2r1 = sh2 + (w * 32 + 16 + li) * 72;

    // claim sorted positions (one atomic per edge, g==0 lanes), write recs
    if (g == 0) {
      int r0 = ok0 ? eidx[E + es0] : 0;
      int r1 = ok1 ? eidx[E + es1] : 0;
      int sn0 = ok0 ? eidx[es0] : 0;
      int sn1 = ok1 ? eidx[es1] : 0;
      int q0 = ok0 ? atomicAdd(&cursor[r0], 1) : 0;
      int q1 = ok1 ? atomicAdd(&cursor[r1], 1) : 0;
      if (ok0) recs[q0] = make_uint2((unsigned)es0, (unsigned)sn0);
      if (ok1) recs[q1] = make_uint2((unsigned)es1, (unsigned)sn1);
      spos[w * 32 + li] = q0;
      spos[w * 32 + 16 + li] = q1;
    }

    // layer 1 (ef reads are eid-sequential)
    {
#pragma unroll
      for (int s = 0; s < 2; ++s) {
        const int e = s ? es1 : es0;
        const bool ok = s ? ok1 : ok0;
        short* h1row = s ? h1r1 : h1r0;
        float4 qa = {0.f, 0.f, 0.f, 0.f}, qb = {0.f, 0.f, 0.f, 0.f};
        if (ok) {
          qa = *reinterpret_cast<const float4*>(ef + (size_t)e * 8);
          qb = *reinterpret_cast<const float4*>(ef + (size_t)e * 8 + 4);
        }
        const float x[8] = {qa.x, qa.y, qa.z, qa.w, qb.x, qb.y, qb.z, qb.w};
        bf16x8 p0, p1;
#pragma unroll
        for (int j = 0; j < 16; ++j) {
          int col = g * 16 + j;
          float a = 0.f;
#pragma unroll
          for (int k = 0; k < 8; ++k) a += x[k] * sW1[k * 64 + col];
          a *= kINV_L1;
          short hv = f2bf(a / (1.f + __expf(-a)));
          if (j < 8) p0[j] = hv; else p1[j - 8] = hv;
        }
        *reinterpret_cast<bf16x8*>(&h1row[g * 16])     = p0;
        *reinterpret_cast<bf16x8*>(&h1row[g * 16 + 8]) = p1;
      }
    }
    WAVE_LDS_SYNC();

    // layer 2 (MFMA, swapped)
    {
      bf16x8 hb0[2], hb1[2];
      hb0[0] = *reinterpret_cast<const bf16x8*>(&h1r0[g * 8]);
      hb1[0] = *reinterpret_cast<const bf16x8*>(&h1r0[32 + g * 8]);
      hb0[1] = *reinterpret_cast<const bf16x8*>(&h1r1[g * 8]);
      hb1[1] = *reinterpret_cast<const bf16x8*>(&h1r1[32 + g * 8]);
#pragma unroll
      for (int ct = 0; ct < 4; ++ct) {
        const short* wrow = &sW2T[(ct * 16 + li) * 72];
        bf16x8 a0 = *reinterpret_cast<const bf16x8*>(&wrow[g * 8]);
        bf16x8 a1 = *reinterpret_cast<const bf16x8*>(&wrow[32 + g * 8]);
#pragma unroll
        for (int s = 0; s < 2; ++s) {
          f32x4 acc = {0.f, 0.f, 0.f, 0.f};
          acc = __builtin_amdgcn_mfma_f32_16x16x32_bf16(a0, hb0[s], acc, 0, 0, 0);
          acc = __builtin_amdgcn_mfma_f32_16x16x32_bf16(a1, hb1[s], acc, 0, 0, 0);
          bf16x4 hq;
#pragma unroll
          for (int r = 0; r < 4; ++r) {
            float a = acc[r] * kINV_L2;
            hq[r] = f2bf(a / (1.f + __expf(-a)));
          }
          *reinterpret_cast<bf16x4*>(&((s ? h2r1 : h2r0)[ct * 16 + g * 4])) = hq;
        }
      }
    }
    WAVE_LDS_SYNC();

    // layer 3 (MFMA, swapped, 2-deep sw pipeline); writes to claimed positions
    {
      const int ps0 = spos[w * 32 + li];
      const int ps1 = spos[w * 32 + 16 + li];
      bf16x8 b0[2], b1[2];
      b0[0] = *reinterpret_cast<const bf16x8*>(&h2r0[g * 8]);
      b1[0] = *reinterpret_cast<const bf16x8*>(&h2r0[32 + g * 8]);
      b0[1] = *reinterpret_cast<const bf16x8*>(&h2r1[g * 8]);
      b1[1] = *reinterpret_cast<const bf16x8*>(&h2r1[32 + g * 8]);

      bf16x8 c0, c1, c2, c3;
      {
        const int rowA = li;
        c0 = *reinterpret_cast<const bf16x8*>(&W3T[(size_t)rowA * 64 + g * 8]);
        c1 = *reinterpret_cast<const bf16x8*>(&W3T[(size_t)rowA * 64 + 32 + g * 8]);
        c2 = *reinterpret_cast<const bf16x8*>(&W3T[(size_t)(rowA + 256) * 64 + g * 8]);
        c3 = *reinterpret_cast<const bf16x8*>(&W3T[(size_t)(rowA + 256) * 64 + 32 + g * 8]);
      }
#pragma unroll
      for (int rt = 0; rt < 16; ++rt) {
        bf16x8 n0, n1, n2, n3;
        const bool pf = (rt < 15);
        if (pf) {
          const int rowA = (rt + 1) * 16 + li;
          n0 = *reinterpret_cast<const bf16x8*>(&W3T[(size_t)rowA * 64 + g * 8]);
          n1 = *reinterpret_cast<const bf16x8*>(&W3T[(size_t)rowA * 64 + 32 + g * 8]);
          n2 = *reinterpret_cast<const bf16x8*>(&W3T[(size_t)(rowA + 256) * 64 + g * 8]);
          n3 = *reinterpret_cast<const bf16x8*>(&W3T[(size_t)(rowA + 256) * 64 + 32 + g * 8]);
        }
#pragma unroll
        for (int s = 0; s < 2; ++s) {
          f32x4 accA = {0.f, 0.f, 0.f, 0.f};
          f32x4 accB = {0.f, 0.f, 0.f, 0.f};
          accA = __builtin_amdgcn_mfma_f32_16x16x32_bf16(c0, b0[s], accA, 0, 0, 0);
          accA = __builtin_amdgcn_mfma_f32_16x16x32_bf16(c1, b1[s], accA, 0, 0, 0);
          accB = __builtin_amdgcn_mfma_f32_16x16x32_bf16(c2, b0[s], accB, 0, 0, 0);
          accB = __builtin_amdgcn_mfma_f32_16x16x32_bf16(c3, b1[s], accB, 0, 0, 0);
          if (s ? ok1 : ok0) {
            uint4 d;
            unsigned* dp = &d.x;
#pragma unroll
            for (int r = 0; r < 4; ++r) {
              unsigned lo = (unsigned)(unsigned short)f2bf(accA[r] * kINV_L3);
              unsigned hi = (unsigned)(unsigned short)f2bf(accB[r] * kINV_L3);
              dp[r] = lo | (hi << 16);
            }
            *reinterpret_cast<uint4*>(
                &tpw2[(size_t)(s ? ps1 : ps0) * 256 + rt * 16 + g * 4]) = d;
          }
        }
        if (pf) { c0 = n0; c1 = n1; c2 = n2; c3 = n3; }
      }
    }
    return;
  }
  blk -= MLP_B;

  // ---------------- UP role: node up-projection (MFMA) ---------------------
  {
    short* lsA = (short*)smem;  // [4][16][136]
    const int nb = blk * 16;

    for (int base = t * 8; base < 16 * 512; base += 256 * 8) {
      int n = base >> 9, j0 = base & 511;
      float vals[8];
      if (nb + n < N) {
        float4 q0 = *reinterpret_cast<const float4*>(nf + (size_t)(nb + n) * 512 + j0);
        float4 q1 = *reinterpret_cast<const float4*>(nf + (size_t)(nb + n) * 512 + j0 + 4);
        vals[0] = q0.x; vals[1] = q0.y; vals[2] = q0.z; vals[3] = q0.w;
        vals[4] = q1.x; vals[5] = q1.y; vals[6] = q1.z; vals[7] = q1.w;
      } else {
#pragma unroll
        for (int e = 0; e < 8; ++e) vals[e] = 0.f;
      }
#pragma unroll
      for (int e = 0; e < 8; ++e) {
        int idx = j0 + e;
        if (idx < 128) {
          lsA[(0 * 16 + n) * 136 + idx] = f2bf(vals[e]);
        } else {
          unsigned q = idx - 128;
          unsigned u = q / 3u;
          unsigned i = q - u * 3u;
          lsA[((1 + i) * 16 + n) * 136 + u] = f2bf(vals[e]);
        }
      }
    }
    __syncthreads();

    const int c = t >> 6;
    const int lane = t & 63;
    const int col = lane & 15;
    const int g = lane >> 4;

    const short* WT = c ? W1T : W0T;

    bf16x8 af[4];
#pragma unroll
    for (int kk = 0; kk < 4; ++kk)
      af[kk] = *reinterpret_cast<const bf16x8*>(&lsA[(c * 16 + col) * 136 + kk * 32 + g * 8]);

#pragma unroll
    for (int nt = 0; nt < 8; ++nt) {
      f32x4 acc = {0.f, 0.f, 0.f, 0.f};
#pragma unroll
      for (int kk = 0; kk < 4; ++kk) {
        bf16x8 bf = *reinterpret_cast<const bf16x8*>(&WT[(size_t)(nt * 16 + col) * 128 + kk * 32 + g * 8]);
        acc = __builtin_amdgcn_mfma_f32_16x16x32_bf16(af[kk], bf, acc, 0, 0, 0);
      }
#pragma unroll
      for (int r = 0; r < 4; ++r) {
        int nd = nb + g * 4 + r;
        if (nd < N) {
          float val = acc[r] * kINV_UP;
          if (c == 0) s_up[(size_t)nd * 128 + nt * 16 + col] = val;
          else        v_up[(size_t)nd * 384 + (c - 1) * 128 + nt * 16 + col] = val;
        }
      }
    }
  }
}

// ---------------------------------------------------------------------------
// K4: gather, one WAVE per node, BOTH sides, CHUNK-OF-4. tpw2 and recs are
// POSITION-indexed -> pure sequential streams; only eattr (16B) and node
// rows (L2/L3-resident) are random. Tail masked by zeroing ea.
// ---------------------------------------------------------------------------
__global__ __launch_bounds__(256) void k_gather(
    const uint2* __restrict__ recs, const int* __restrict__ offs,
    const unsigned* __restrict__ tpw2, const float* __restrict__ eattr,
    const float* __restrict__ s_up, const float* __restrict__ v_up,
    float* __restrict__ Ms, float* __restrict__ Mv, int N) {
  const int t = threadIdx.x;
  const int n = blockIdx.x * 4 + (t >> 6);
  if (n >= N) return;
  const int l = t & 63;
  const int u0 = l * 2;

  float aMsS0 = 0.f, aMsS1 = 0.f;   // m0 -> Ms[0:128)
  float aMsV0 = 0.f, aMsV1 = 0.f;   // m1 -> Ms[128:256)
  float aVs[3][2] = {};             // m2 -> Mv[i][0:128)
  float aVv[3][2] = {};             // m3 -> Mv[i][128:256)

  const int e0 = offs[n], e1 = offs[n + 1];
  const int last = e1 - 1;

  for (int p0 = e0; p0 < e1; p0 += 4) {
    const int p1 = min(p0 + 1, last);
    const int p2 = min(p0 + 2, last);
    const int p3 = min(p0 + 3, last);
    uint2 rc0 = recs[p0];
    uint2 rc1 = recs[p1];
    uint2 rc2 = recs[p2];
    uint2 rc3 = recs[p3];

    float4 ea0 = *reinterpret_cast<const float4*>(eattr + (size_t)rc0.x * 4);
    float4 ea1 = *reinterpret_cast<const float4*>(eattr + (size_t)rc1.x * 4);
    float4 ea2 = *reinterpret_cast<const float4*>(eattr + (size_t)rc2.x * 4);
    float4 ea3 = *reinterpret_cast<const float4*>(eattr + (size_t)rc3.x * 4);
    uint2 qs0 = *reinterpret_cast<const uint2*>(tpw2 + (size_t)p0 * 256 + u0);
    uint2 qs1 = *reinterpret_cast<const uint2*>(tpw2 + (size_t)p1 * 256 + u0);
    uint2 qs2 = *reinterpret_cast<const uint2*>(tpw2 + (size_t)p2 * 256 + u0);
    uint2 qs3 = *reinterpret_cast<const uint2*>(tpw2 + (size_t)p3 * 256 + u0);
    uint2 qv0 = *reinterpret_cast<const uint2*>(tpw2 + (size_t)p0 * 256 + 128 + u0);
    uint2 qv1 = *reinterpret_cast<const uint2*>(tpw2 + (size_t)p1 * 256 + 128 + u0);
    uint2 qv2 = *reinterpret_cast<const uint2*>(tpw2 + (size_t)p2 * 256 + 128 + u0);
    uint2 qv3 = *reinterpret_cast<const uint2*>(tpw2 + (size_t)p3 * 256 + 128 + u0);
    float2 xs0 = *reinterpret_cast<const float2*>(s_up + (size_t)rc0.y * 128 + u0);
    float2 xs1 = *reinterpret_cast<const float2*>(s_up + (size_t)rc1.y * 128 + u0);
    float2 xs2 = *reinterpret_cast<const float2*>(s_up + (size_t)rc2.y * 128 + u0);
    float2 xs3 = *reinterpret_cast<const float2*>(s_up + (size_t)rc3.y * 128 + u0);
    const float* xvp0 = v_up + (size_t)rc0.y * 384 + u0;
    const float* xvp1 = v_up + (size_t)rc1.y * 384 + u0;
    const float* xvp2 = v_up + (size_t)rc2.y * 384 + u0;
    const float* xvp3 = v_up + (size_t)rc3.y * 384 + u0;
    float2 xa0 = *reinterpret_cast<const float2*>(xvp0);
    float2 xb0 = *reinterpret_cast<const float2*>(xvp0 + 128);
    float2 xc0 = *reinterpret_cast<const float2*>(xvp0 + 256);
    float2 xa1 = *reinterpret_cast<const float2*>(xvp1);
    float2 xb1 = *reinterpret_cast<const float2*>(xvp1 + 128);
    float2 xc1 = *reinterpret_cast<const float2*>(xvp1 + 256);
    float2 xa2 = *reinterpret_cast<const float2*>(xvp2);
    float2 xb2 = *reinterpret_cast<const float2*>(xvp2 + 128);
    float2 xc2 = *reinterpret_cast<const float2*>(xvp2 + 256);
    float2 xa3 = *reinterpret_cast<const float2*>(xvp3);
    float2 xb3 = *reinterpret_cast<const float2*>(xvp3 + 128);
    float2 xc3 = *reinterpret_cast<const float2*>(xvp3 + 256);

    const int m = e1 - p0;
    if (m < 4) {
      float k1 = (m > 1) ? 1.f : 0.f;
      float k2 = (m > 2) ? 1.f : 0.f;
      ea1.x *= k1; ea1.y *= k1; ea1.z *= k1; ea1.w *= k1;
      ea2.x *= k2; ea2.y *= k2; ea2.z *= k2; ea2.w *= k2;
      ea3.x = 0.f; ea3.y = 0.f; ea3.z = 0.f; ea3.w = 0.f;
    }

#define ACC_EDGE(EA, QS, QV, XS, XA, XB, XC)                                   \
    {                                                                          \
      float tA0 = __uint_as_float(QS.x << 16);                                 \
      float tB0 = __uint_as_float(QS.x & 0xFFFF0000u);                         \
      float tA1 = __uint_as_float(QS.y << 16);                                 \
      float tB1 = __uint_as_float(QS.y & 0xFFFF0000u);                         \
      aMsS0 += tA0 * XS.x * EA.x;                                              \
      aMsS1 += tA1 * XS.y * EA.x;                                              \
      float wc0 = tB0 * XS.x, wc1 = tB1 * XS.y;                                \
      aVs[0][0] += wc0 * EA.y; aVs[0][1] += wc1 * EA.y;                        \
      aVs[1][0] += wc0 * EA.z; aVs[1][1] += wc1 * EA.z;                        \
      aVs[2][0] += wc0 * EA.w; aVs[2][1] += wc1 * EA.w;                        \
      float uA0 = __uint_as_float(QV.x << 16);                                 \
      float uB0 = __uint_as_float(QV.x & 0xFFFF0000u);                         \
      float uA1 = __uint_as_float(QV.y << 16);                                 \
      float uB1 = __uint_as_float(QV.y & 0xFFFF0000u);                         \
      float dot0 = XA.x * EA.y + XB.x * EA.z + XC.x * EA.w;                    \
      float dot1 = XA.y * EA.y + XB.y * EA.z + XC.y * EA.w;                    \
      aMsV0 += uA0 * dot0 * kINV_SQ3;                                          \
      aMsV1 += uA1 * dot1 * kINV_SQ3;                                          \
      float wd0 = uB0 * EA.x, wd1 = uB1 * EA.x;                                \
      aVv[0][0] += wd0 * XA.x; aVv[0][1] += wd1 * XA.y;                        \
      aVv[1][0] += wd0 * XB.x; aVv[1][1] += wd1 * XB.y;                        \
      aVv[2][0] += wd0 * XC.x; aVv[2][1] += wd1 * XC.y;                        \
    }

    ACC_EDGE(ea0, qs0, qv0, xs0, xa0, xb0, xc0)
    ACC_EDGE(ea1, qs1, qv1, xs1, xa1, xb1, xc1)
    ACC_EDGE(ea2, qs2, qv2, xs2, xa2, xb2, xc2)
    ACC_EDGE(ea3, qs3, qv3, xs3, xa3, xb3, xc3)
#undef ACC_EDGE
  }

  *reinterpret_cast<float2*>(Ms + (size_t)n * 256 + u0)       = make_float2(aMsS0, aMsS1);
  *reinterpret_cast<float2*>(Ms + (size_t)n * 256 + 128 + u0) = make_float2(aMsV0, aMsV1);
#pragma unroll
  for (int i = 0; i < 3; ++i) {
    *reinterpret_cast<float2*>(Mv + (size_t)n * 768 + i * 256 + u0) =
        make_float2(aVs[i][0], aVs[i][1]);
    *reinterpret_cast<float2*>(Mv + (size_t)n * 768 + i * 256 + 128 + u0) =
        make_float2(aVv[i][0], aVv[i][1]);
  }
}

// ---------------------------------------------------------------------------
// K5 (MFMA): fused lin + skip + combine (unchanged — passed).
// ---------------------------------------------------------------------------
__global__ __launch_bounds__(256) void k_linskip(
    const float* __restrict__ Ms, const float* __restrict__ Mv,
    const short* __restrict__ Wl0T, const short* __restrict__ Wl1T,
    const short* __restrict__ Wsk0T, const short* __restrict__ Wsk1T,
    const float* __restrict__ attrs, const float* __restrict__ upd,
    float* __restrict__ out, int N) {
  __shared__ __align__(16) short lsA[4][16][264];
  __shared__ __align__(16) short lsS[4][16][136];
  __shared__ float sat[16][4];
  const int nb = blockIdx.x * 16;
  const int t = threadIdx.x;

  for (int base = t * 4; base < 16 * 1024; base += 1024) {
    int n = base >> 10, j = base & 1023;
    int comp = j >> 8, u = j & 255;
    float4 q = {0.f, 0.f, 0.f, 0.f};
    if (nb + n < N) {
      const float* src = (comp == 0) ? (Ms + (size_t)(nb + n) * 256 + u)
                                     : (Mv + (size_t)(nb + n) * 768 + (size_t)(comp - 1) * 256 + u);
      q = *reinterpret_cast<const float4*>(src);
    }
    lsA[comp][n][u + 0] = f2bf(q.x);
    lsA[comp][n][u + 1] = f2bf(q.y);
    lsA[comp][n][u + 2] = f2bf(q.z);
    lsA[comp][n][u + 3] = f2bf(q.w);
  }
  if (t < 64) {
    int n = t >> 2, v = t & 3;
    sat[n][v] = (nb + n < N) ? attrs[(size_t)(nb + n) * 4 + v] : 0.f;
  }
  __syncthreads();

  const int c = t >> 6;
  const int lane = t & 63;
  const int col = lane & 15;
  const int g = lane >> 4;

  const short* WLT = c ? Wl1T : Wl0T;
  const short* WST = c ? Wsk1T : Wsk0T;

  bf16x8 af1[8];
#pragma unroll
  for (int kk = 0; kk < 8; ++kk)
    af1[kk] = *reinterpret_cast<const bf16x8*>(&lsA[c][col][kk * 32 + g * 8]);

  f32x4 Sreg[8];
#pragma unroll
  for (int nt = 0; nt < 8; ++nt) {
    f32x4 acc = {0.f, 0.f, 0.f, 0.f};
#pragma unroll
    for (int kk = 0; kk < 8; ++kk) {
      bf16x8 bf = *reinterpret_cast<const bf16x8*>(&WLT[(size_t)(nt * 16 + col) * 256 + kk * 32 + g * 8]);
      acc = __builtin_amdgcn_mfma_f32_16x16x32_bf16(af1[kk], bf, acc, 0, 0, 0);
    }
#pragma unroll
    for (int r = 0; r < 4; ++r) acc[r] *= kINV_LIN;
    Sreg[nt] = acc;
#pragma unroll
    for (int r = 0; r < 4; ++r)
      lsS[c][g * 4 + r][nt * 16 + col] = f2bf(acc[r]);
  }

  float satr[4][4];
#pragma unroll
  for (int r = 0; r < 4; ++r)
#pragma unroll
    for (int v = 0; v < 4; ++v) satr[r][v] = sat[g * 4 + r][v];

  __syncthreads();

  bf16x8 af2[4];
#pragma unroll
  for (int kk = 0; kk < 4; ++kk)
    af2[kk] = *reinterpret_cast<const bf16x8*>(&lsS[c][col][kk * 32 + g * 8]);

  const float p = upd[0];
  const float cc = 1.f / (1.f + __expf(-p));
  const float c_old = rsqrtf(cc * cc + 1.f);
  const float c_new = cc * c_old;

#pragma unroll
  for (int nt = 0; nt < 8; ++nt) {
    float fin[4] = {0.f, 0.f, 0.f, 0.f};
#pragma unroll
    for (int v = 0; v < 4; ++v) {
      f32x4 tmp = {0.f, 0.f, 0.f, 0.f};
#pragma unroll
      for (int kk = 0; kk < 4; ++kk) {
        bf16x8 bf = *reinterpret_cast<const bf16x8*>(&WST[(size_t)(nt * 16 + col) * 512 + v * 128 + kk * 32 + g * 8]);
        tmp = __builtin_amdgcn_mfma_f32_16x16x32_bf16(af2[kk], bf, tmp, 0, 0, 0);
      }
#pragma unroll
      for (int r = 0; r < 4; ++r) fin[r] += satr[r][v] * tmp[r];
    }
#pragma unroll
    for (int r = 0; r < 4; ++r) {
      int nd = nb + g * 4 + r;
      if (nd < N) {
        float val = c_old * Sreg[nt][r] + c_new * fin[r] * kINV_SK;
        out[((size_t)nd * 128 + nt * 16 + col) * 4 + c] = val;
      }
    }
  }
}

extern "C" void kernel_launch(void* const* d_in, const int* in_sizes, int n_in,
                              void* d_out, int out_size, void* d_ws, size_t ws_size,
                              hipStream_t stream) {
  const float* node_attrs = (const float*)d_in[0];
  const float* node_feats = (const float*)d_in[1];
  const float* edge_attrs = (const float*)d_in[2];
  const float* edge_feats = (const float*)d_in[3];
  const int*   edge_index = (const int*)d_in[4];
  const float* W_up0  = (const float*)d_in[5];
  const float* W_up1  = (const float*)d_in[6];
  const float* W_mlp1 = (const float*)d_in[7];
  const float* W_mlp2 = (const float*)d_in[8];
  const float* W_mlp3 = (const float*)d_in[9];
  const float* W_lin0 = (const float*)d_in[10];
  const float* W_lin1 = (const float*)d_in[11];
  const float* W_skip0 = (const float*)d_in[12];
  const float* W_skip1 = (const float*)d_in[13];
  const float* upd = (const float*)d_in[14];
  float* out = (float*)d_out;

  const int N = in_sizes[0] / 4;
  const int E = in_sizes[4] / 2;

  float* ws = (float*)d_ws;
  float* s_up = ws;                          // N*128
  float* v_up = s_up + (size_t)N * 128;      // N*384  [n][i][u]
  float* Ms   = v_up + (size_t)N * 384;      // N*256
  float* Mv   = Ms + (size_t)N * 256;        // N*768  [n][i][u]
  int* cnt    = (int*)(Mv + (size_t)N * 768); // N
  int* offs   = cnt + N;                      // N+1
  int* cursor = offs + N + 1;                 // N
  uint2* recs = (uint2*)((((uintptr_t)(cursor + N)) + 7) & ~(uintptr_t)7);  // E uint2

  short* wbase = (short*)((((uintptr_t)(recs + E)) + 15) & ~(uintptr_t)15);
  short* W0T   = wbase;            // 128*128
  short* W1T   = W0T + 16384;      // 128*128
  short* Wl0T  = W1T + 16384;      // 128*256
  short* Wl1T  = Wl0T + 32768;     // 128*256
  short* Wsk0T = Wl1T + 32768;     // 128*512
  short* Wsk1T = Wsk0T + 65536;    // 128*512
  short* W2T   = Wsk1T + 65536;    // 64*64
  short* W3T   = W2T + 4096;       // 512*64
  unsigned* tpw2 = (unsigned*)(W3T + 32768); // E*256 dwords

  const int CVT_B = (266240 + 255) / 256;      // 1040
  const int CNT_B = (E + 255) / 256;
  const int MLP_B = (E + 127) / 128;
  const int UP_B  = (N + 15) / 16;

  hipMemsetAsync(cnt, 0, (size_t)N * sizeof(int), stream);

  k_cvtcnt<<<CVT_B + CNT_B, 256, 0, stream>>>(
      W_up0, W_up1, W_lin0, W_lin1, W_skip0, W_skip1, W_mlp2, W_mlp3,
      W0T, W1T, Wl0T, Wl1T, Wsk0T, Wsk1T, W2T, W3T,
      edge_index, cnt, E, CVT_B);
  k_scan<<<1, 1024, 0, stream>>>(cnt, offs, cursor, N);
  k_fused3<<<MLP_B + UP_B, 256, 0, stream>>>(
      edge_index, cursor, recs,
      node_feats, W0T, W1T, s_up, v_up,
      edge_feats, W_mlp1, W2T, W3T, tpw2, N, E, MLP_B);
  k_gather<<<(N + 3) / 4, 256, 0, stream>>>(recs, offs, tpw2, edge_attrs,
                                            s_up, v_up, Ms, Mv, N);
  k_linskip<<<(N + 15) / 16, 256, 0, stream>>>(Ms, Mv, Wl0T, Wl1T, Wsk0T, Wsk1T,
                                               node_attrs, upd, out, N);
}

// Round 15
// 268.012 us; speedup vs baseline: 1.0340x; 1.0295x over previous
//
#include <hip/hip_runtime.h>

#define MUL 128

typedef __attribute__((ext_vector_type(8))) short bf16x8;
typedef __attribute__((ext_vector_type(4))) short bf16x4;
typedef __attribute__((ext_vector_type(4))) float f32x4;

__device__ __constant__ float kINV_UP   = 0.08838834764831845f;  // 1/sqrt(128)
__device__ __constant__ float kINV_L1   = 0.35355339059327373f;  // 1/sqrt(8)
__device__ __constant__ float kINV_L2   = 0.125f;                // 1/sqrt(64)
__device__ __constant__ float kINV_L3   = 0.125f;
__device__ __constant__ float kINV_LIN  = 0.00390625f;           // 1/(sqrt(256)*16)
__device__ __constant__ float kINV_SK   = 0.044194173824159216f; // 1/sqrt(512)
__device__ __constant__ float kINV_SQ3  = 0.5773502691896258f;   // 1/sqrt(3)

// intra-wave LDS ordering: drain ds ops; memory clobber keeps ds_reads below.
#define WAVE_LDS_SYNC() asm volatile("s_waitcnt lgkmcnt(0)" ::: "memory")

static __device__ __forceinline__ short f2bf(float f) {
  unsigned u = __float_as_uint(f);
  unsigned r = (u + 0x7FFFu + ((u >> 16) & 1u)) >> 16;  // RNE
  return (short)r;
}

// ---------------------------------------------------------------------------
// K1 (fused): weight conversion (blocks [0,CVT_B)) | receiver count (rest).
// ---------------------------------------------------------------------------
__global__ __launch_bounds__(256) void k_cvtcnt(
    const float* __restrict__ W_up0, const float* __restrict__ W_up1,
    const float* __restrict__ W_lin0, const float* __restrict__ W_lin1,
    const float* __restrict__ W_sk0, const float* __restrict__ W_sk1,
    const float* __restrict__ W_mlp2, const float* __restrict__ W_mlp3,
    short* __restrict__ W0T, short* __restrict__ W1T,
    short* __restrict__ Wl0T, short* __restrict__ Wl1T,
    short* __restrict__ Wsk0T, short* __restrict__ Wsk1T,
    short* __restrict__ W2T, short* __restrict__ W3T,
    const int* __restrict__ eidx, int* __restrict__ cnt, int E, int CVT_B) {
  int blk = blockIdx.x;
  if (blk >= CVT_B) {
    int e = (blk - CVT_B) * 256 + threadIdx.x;
    if (e < E) atomicAdd(&cnt[eidx[E + e]], 1);
    return;
  }
  int id = blk * 256 + threadIdx.x;
  if (id < 16384) {
    int w = id >> 7, u = id & 127;
    W0T[id] = f2bf(W_up0[u * 128 + w]);
    return;
  }
  id -= 16384;
  if (id < 16384) {
    int w = id >> 7, u = id & 127;
    W1T[id] = f2bf(W_up1[u * 128 + w]);
    return;
  }
  id -= 16384;
  if (id < 32768) {
    int w = id >> 8, u = id & 255;
    Wl0T[id] = f2bf(W_lin0[u * 128 + w]);
    return;
  }
  id -= 32768;
  if (id < 32768) {
    int w = id >> 8, u = id & 255;
    Wl1T[id] = f2bf(W_lin1[u * 128 + w]);
    return;
  }
  id -= 32768;
  if (id < 65536) {
    int w = id >> 9, k = id & 511;
    int v = k >> 7, u = k & 127;
    Wsk0T[id] = f2bf(W_sk0[(u * 4 + v) * 128 + w]);
    return;
  }
  id -= 65536;
  if (id < 65536) {
    int w = id >> 9, k = id & 511;
    int v = k >> 7, u = k & 127;
    Wsk1T[id] = f2bf(W_sk1[(u * 4 + v) * 128 + w]);
    return;
  }
  id -= 65536;
  if (id < 4096) {
    int c = id >> 6, k = id & 63;
    W2T[id] = f2bf(W_mlp2[k * 64 + c]);
    return;
  }
  id -= 4096;
  if (id < 32768) {
    int c = id >> 6, k = id & 63;
    W3T[id] = f2bf(W_mlp3[k * 512 + c]);
  }
}

// ---------------------------------------------------------------------------
// K2: exclusive scan over counts (1 block).
// ---------------------------------------------------------------------------
__global__ __launch_bounds__(1024) void k_scan(const int* __restrict__ cnt,
                                               int* __restrict__ offs,
                                               int* __restrict__ cursor, int N) {
  __shared__ int part[1024];
  const int t = threadIdx.x;
  int CH = (N + 1023) >> 10;
  if (CH > 16) CH = 16;
  const int base = t * CH;
  int loc[16];
  int s = 0;
  for (int i = 0; i < CH; ++i) {
    int idx = base + i;
    loc[i] = (idx < N) ? cnt[idx] : 0;
    s += loc[i];
  }
  part[t] = s;
  __syncthreads();
  for (int off = 1; off < 1024; off <<= 1) {
    int v = part[t];
    int add = (t >= off) ? part[t - off] : 0;
    __syncthreads();
    part[t] = v + add;
    __syncthreads();
  }
  int excl = part[t] - s;
  for (int i = 0; i < CH; ++i) {
    int idx = base + i;
    if (idx < N) { offs[idx] = excl; cursor[idx] = excl; }
    excl += loc[i];
  }
  if (t == 1023) offs[N] = part[1023];
}

// ---------------------------------------------------------------------------
// K3 (fused, block-range dispatch):
//   [0, MLP_B)            : per-edge MLP -> tpw2[eid], 128 edges/block,
//                           32 edges/WAVE (2 MFMA B-sets), sw-pipelined L3
//   [MLP_B, MLP_B+UP_B)   : node up-projection (MFMA)
//   [MLP_B+UP_B, ...)     : scatter -> recs[p] = {eid, sender}
// ---------------------------------------------------------------------------
__global__ __launch_bounds__(256) void k_fused3(
    const int* __restrict__ eidx, int* __restrict__ cursor, uint2* __restrict__ recs,
    const float* __restrict__ nf, const short* __restrict__ W0T,
    const short* __restrict__ W1T, float* __restrict__ s_up, float* __restrict__ v_up,
    const float* __restrict__ ef, const float* __restrict__ W1f,
    const short* __restrict__ W2T, const short* __restrict__ W3T,
    unsigned* __restrict__ tpw2, int N, int E, int MLP_B, int UP_B) {
  __shared__ __align__(16) char smem[48128];
  const int t = threadIdx.x;
  int blk = blockIdx.x;

  if (blk < MLP_B) {
    // ---------------- MLP role: 128 edges/block, 32 edges per wave ---------
    float* sW1  = (float*)smem;
    short* sW2T = (short*)(smem + 2048);
    short* sh1  = (short*)(smem + 11264);
    short* sh2  = (short*)(smem + 29696);

    for (int i = t * 4; i < 512; i += 1024)
      *reinterpret_cast<float4*>(&sW1[i]) = *reinterpret_cast<const float4*>(W1f + i);
    for (int i = t * 8; i < 4096; i += 2048) {
      int r = i >> 6, c = i & 63;
      *reinterpret_cast<bf16x8*>(&sW2T[r * 72 + c]) =
          *reinterpret_cast<const bf16x8*>(&W2T[r * 64 + c]);
    }
    __syncthreads();  // weights visible; no more block barriers

    const int w = t >> 6, l = t & 63, li = l & 15, g = l >> 4;
    const int eb = blk * 128 + w * 32;
    const int es0 = eb + li, es1 = eb + 16 + li;
    short* h1r0 = sh1 + (w * 32 + li) * 72;
    short* h1r1 = sh1 + (w * 32 + 16 + li) * 72;
    short* h2r0 = sh2 + (w * 32 + li) * 72;
    short* h2r1 = sh2 + (w * 32 + 16 + li) * 72;

    // layer 1
    {
#pragma unroll
      for (int s = 0; s < 2; ++s) {
        const int e = s ? es1 : es0;
        short* h1row = s ? h1r1 : h1r0;
        float4 qa = {0.f, 0.f, 0.f, 0.f}, qb = {0.f, 0.f, 0.f, 0.f};
        if (e < E) {
          qa = *reinterpret_cast<const float4*>(ef + (size_t)e * 8);
          qb = *reinterpret_cast<const float4*>(ef + (size_t)e * 8 + 4);
        }
        const float x[8] = {qa.x, qa.y, qa.z, qa.w, qb.x, qb.y, qb.z, qb.w};
        bf16x8 p0, p1;
#pragma unroll
        for (int j = 0; j < 16; ++j) {
          int col = g * 16 + j;
          float a = 0.f;
#pragma unroll
          for (int k = 0; k < 8; ++k) a += x[k] * sW1[k * 64 + col];
          a *= kINV_L1;
          short hv = f2bf(a / (1.f + __expf(-a)));
          if (j < 8) p0[j] = hv; else p1[j - 8] = hv;
        }
        *reinterpret_cast<bf16x8*>(&h1row[g * 16])     = p0;
        *reinterpret_cast<bf16x8*>(&h1row[g * 16 + 8]) = p1;
      }
    }
    WAVE_LDS_SYNC();

    // layer 2 (MFMA, swapped)
    {
      bf16x8 hb0[2], hb1[2];
      hb0[0] = *reinterpret_cast<const bf16x8*>(&h1r0[g * 8]);
      hb1[0] = *reinterpret_cast<const bf16x8*>(&h1r0[32 + g * 8]);
      hb0[1] = *reinterpret_cast<const bf16x8*>(&h1r1[g * 8]);
      hb1[1] = *reinterpret_cast<const bf16x8*>(&h1r1[32 + g * 8]);
#pragma unroll
      for (int ct = 0; ct < 4; ++ct) {
        const short* wrow = &sW2T[(ct * 16 + li) * 72];
        bf16x8 a0 = *reinterpret_cast<const bf16x8*>(&wrow[g * 8]);
        bf16x8 a1 = *reinterpret_cast<const bf16x8*>(&wrow[32 + g * 8]);
#pragma unroll
        for (int s = 0; s < 2; ++s) {
          f32x4 acc = {0.f, 0.f, 0.f, 0.f};
          acc = __builtin_amdgcn_mfma_f32_16x16x32_bf16(a0, hb0[s], acc, 0, 0, 0);
          acc = __builtin_amdgcn_mfma_f32_16x16x32_bf16(a1, hb1[s], acc, 0, 0, 0);
          bf16x4 hq;
#pragma unroll
          for (int r = 0; r < 4; ++r) {
            float a = acc[r] * kINV_L2;
            hq[r] = f2bf(a / (1.f + __expf(-a)));
          }
          *reinterpret_cast<bf16x4*>(&((s ? h2r1 : h2r0)[ct * 16 + g * 4])) = hq;
        }
      }
    }
    WAVE_LDS_SYNC();

    // layer 3 (MFMA, swapped, 2-deep software pipeline on W3T A-fragments)
    {
      bf16x8 b0[2], b1[2];
      b0[0] = *reinterpret_cast<const bf16x8*>(&h2r0[g * 8]);
      b1[0] = *reinterpret_cast<const bf16x8*>(&h2r0[32 + g * 8]);
      b0[1] = *reinterpret_cast<const bf16x8*>(&h2r1[g * 8]);
      b1[1] = *reinterpret_cast<const bf16x8*>(&h2r1[32 + g * 8]);
      const bool ok0 = es0 < E, ok1 = es1 < E;

      bf16x8 c0, c1, c2, c3;
      {
        const int rowA = li;
        c0 = *reinterpret_cast<const bf16x8*>(&W3T[(size_t)rowA * 64 + g * 8]);
        c1 = *reinterpret_cast<const bf16x8*>(&W3T[(size_t)rowA * 64 + 32 + g * 8]);
        c2 = *reinterpret_cast<const bf16x8*>(&W3T[(size_t)(rowA + 256) * 64 + g * 8]);
        c3 = *reinterpret_cast<const bf16x8*>(&W3T[(size_t)(rowA + 256) * 64 + 32 + g * 8]);
      }
#pragma unroll
      for (int rt = 0; rt < 16; ++rt) {
        bf16x8 n0, n1, n2, n3;
        const bool pf = (rt < 15);
        if (pf) {
          const int rowA = (rt + 1) * 16 + li;
          n0 = *reinterpret_cast<const bf16x8*>(&W3T[(size_t)rowA * 64 + g * 8]);
          n1 = *reinterpret_cast<const bf16x8*>(&W3T[(size_t)rowA * 64 + 32 + g * 8]);
          n2 = *reinterpret_cast<const bf16x8*>(&W3T[(size_t)(rowA + 256) * 64 + g * 8]);
          n3 = *reinterpret_cast<const bf16x8*>(&W3T[(size_t)(rowA + 256) * 64 + 32 + g * 8]);
        }
#pragma unroll
        for (int s = 0; s < 2; ++s) {
          f32x4 accA = {0.f, 0.f, 0.f, 0.f};
          f32x4 accB = {0.f, 0.f, 0.f, 0.f};
          accA = __builtin_amdgcn_mfma_f32_16x16x32_bf16(c0, b0[s], accA, 0, 0, 0);
          accA = __builtin_amdgcn_mfma_f32_16x16x32_bf16(c1, b1[s], accA, 0, 0, 0);
          accB = __builtin_amdgcn_mfma_f32_16x16x32_bf16(c2, b0[s], accB, 0, 0, 0);
          accB = __builtin_amdgcn_mfma_f32_16x16x32_bf16(c3, b1[s], accB, 0, 0, 0);
          if (s ? ok1 : ok0) {
            uint4 d;
            unsigned* dp = &d.x;
#pragma unroll
            for (int r = 0; r < 4; ++r) {
              unsigned lo = (unsigned)(unsigned short)f2bf(accA[r] * kINV_L3);
              unsigned hi = (unsigned)(unsigned short)f2bf(accB[r] * kINV_L3);
              dp[r] = lo | (hi << 16);
            }
            *reinterpret_cast<uint4*>(
                &tpw2[(size_t)(s ? es1 : es0) * 256 + rt * 16 + g * 4]) = d;
          }
        }
        if (pf) { c0 = n0; c1 = n1; c2 = n2; c3 = n3; }
      }
    }
    return;
  }
  blk -= MLP_B;

  if (blk < UP_B) {
    // ---------------- UP role: node up-projection (MFMA) -------------------
    short* lsA = (short*)smem;  // [4][16][136]
    const int nb = blk * 16;

    for (int base = t * 8; base < 16 * 512; base += 256 * 8) {
      int n = base >> 9, j0 = base & 511;
      float vals[8];
      if (nb + n < N) {
        float4 q0 = *reinterpret_cast<const float4*>(nf + (size_t)(nb + n) * 512 + j0);
        float4 q1 = *reinterpret_cast<const float4*>(nf + (size_t)(nb + n) * 512 + j0 + 4);
        vals[0] = q0.x; vals[1] = q0.y; vals[2] = q0.z; vals[3] = q0.w;
        vals[4] = q1.x; vals[5] = q1.y; vals[6] = q1.z; vals[7] = q1.w;
      } else {
#pragma unroll
        for (int e = 0; e < 8; ++e) vals[e] = 0.f;
      }
#pragma unroll
      for (int e = 0; e < 8; ++e) {
        int idx = j0 + e;
        if (idx < 128) {
          lsA[(0 * 16 + n) * 136 + idx] = f2bf(vals[e]);
        } else {
          unsigned q = idx - 128;
          unsigned u = q / 3u;
          unsigned i = q - u * 3u;
          lsA[((1 + i) * 16 + n) * 136 + u] = f2bf(vals[e]);
        }
      }
    }
    __syncthreads();

    const int c = t >> 6;
    const int lane = t & 63;
    const int col = lane & 15;
    const int g = lane >> 4;

    const short* WT = c ? W1T : W0T;

    bf16x8 af[4];
#pragma unroll
    for (int kk = 0; kk < 4; ++kk)
      af[kk] = *reinterpret_cast<const bf16x8*>(&lsA[(c * 16 + col) * 136 + kk * 32 + g * 8]);

#pragma unroll
    for (int nt = 0; nt < 8; ++nt) {
      f32x4 acc = {0.f, 0.f, 0.f, 0.f};
#pragma unroll
      for (int kk = 0; kk < 4; ++kk) {
        bf16x8 bf = *reinterpret_cast<const bf16x8*>(&WT[(size_t)(nt * 16 + col) * 128 + kk * 32 + g * 8]);
        acc = __builtin_amdgcn_mfma_f32_16x16x32_bf16(af[kk], bf, acc, 0, 0, 0);
      }
#pragma unroll
      for (int r = 0; r < 4; ++r) {
        int nd = nb + g * 4 + r;
        if (nd < N) {
          float val = acc[r] * kINV_UP;
          if (c == 0) s_up[(size_t)nd * 128 + nt * 16 + col] = val;
          else        v_up[(size_t)nd * 384 + (c - 1) * 128 + nt * 16 + col] = val;
        }
      }
    }
    return;
  }
  blk -= UP_B;

  // ---------------- SCATTER role: recs[p] = {eid, sender} -------------------
  int e = blk * 256 + t;
  if (e < E) {
    int r = eidx[E + e];
    int snd = eidx[e];
    int p = atomicAdd(&cursor[r], 1);
    recs[p] = make_uint2((unsigned)e, (unsigned)snd);
  }
}

// ---------------------------------------------------------------------------
// K4: gather, one WAVE per node, BOTH sides, CHUNK-OF-4 edges per iteration:
// all ~28 loads for the chunk issued up front (independent -> deep MLP),
// tail masked by zeroing ea (every message term factors through ea).
// Lane owns cols {u0,u0+1} of each 128-half. No LDS, no barriers.
// ---------------------------------------------------------------------------
__global__ __launch_bounds__(256) void k_gather(
    const uint2* __restrict__ recs, const int* __restrict__ offs,
    const unsigned* __restrict__ tpw2, const float* __restrict__ eattr,
    const float* __restrict__ s_up, const float* __restrict__ v_up,
    float* __restrict__ Ms, float* __restrict__ Mv, int N) {
  const int t = threadIdx.x;
  const int n = blockIdx.x * 4 + (t >> 6);
  if (n >= N) return;
  const int l = t & 63;
  const int u0 = l * 2;

  float aMsS0 = 0.f, aMsS1 = 0.f;   // m0 -> Ms[0:128)
  float aMsV0 = 0.f, aMsV1 = 0.f;   // m1 -> Ms[128:256)
  float aVs[3][2] = {};             // m2 -> Mv[i][0:128)
  float aVv[3][2] = {};             // m3 -> Mv[i][128:256)

  const int e0 = offs[n], e1 = offs[n + 1];

  for (int p0 = e0; p0 < e1; p0 += 4) {
    const int last = e1 - 1;
    // chunk records (broadcast loads, clamped)
    uint2 rc0 = recs[p0];
    uint2 rc1 = recs[min(p0 + 1, last)];
    uint2 rc2 = recs[min(p0 + 2, last)];
    uint2 rc3 = recs[min(p0 + 3, last)];

    // issue ALL chunk loads (independent)
    float4 ea0 = *reinterpret_cast<const float4*>(eattr + (size_t)rc0.x * 4);
    float4 ea1 = *reinterpret_cast<const float4*>(eattr + (size_t)rc1.x * 4);
    float4 ea2 = *reinterpret_cast<const float4*>(eattr + (size_t)rc2.x * 4);
    float4 ea3 = *reinterpret_cast<const float4*>(eattr + (size_t)rc3.x * 4);
    uint2 qs0 = *reinterpret_cast<const uint2*>(tpw2 + (size_t)rc0.x * 256 + u0);
    uint2 qs1 = *reinterpret_cast<const uint2*>(tpw2 + (size_t)rc1.x * 256 + u0);
    uint2 qs2 = *reinterpret_cast<const uint2*>(tpw2 + (size_t)rc2.x * 256 + u0);
    uint2 qs3 = *reinterpret_cast<const uint2*>(tpw2 + (size_t)rc3.x * 256 + u0);
    uint2 qv0 = *reinterpret_cast<const uint2*>(tpw2 + (size_t)rc0.x * 256 + 128 + u0);
    uint2 qv1 = *reinterpret_cast<const uint2*>(tpw2 + (size_t)rc1.x * 256 + 128 + u0);
    uint2 qv2 = *reinterpret_cast<const uint2*>(tpw2 + (size_t)rc2.x * 256 + 128 + u0);
    uint2 qv3 = *reinterpret_cast<const uint2*>(tpw2 + (size_t)rc3.x * 256 + 128 + u0);
    float2 xs0 = *reinterpret_cast<const float2*>(s_up + (size_t)rc0.y * 128 + u0);
    float2 xs1 = *reinterpret_cast<const float2*>(s_up + (size_t)rc1.y * 128 + u0);
    float2 xs2 = *reinterpret_cast<const float2*>(s_up + (size_t)rc2.y * 128 + u0);
    float2 xs3 = *reinterpret_cast<const float2*>(s_up + (size_t)rc3.y * 128 + u0);
    const float* xvp0 = v_up + (size_t)rc0.y * 384 + u0;
    const float* xvp1 = v_up + (size_t)rc1.y * 384 + u0;
    const float* xvp2 = v_up + (size_t)rc2.y * 384 + u0;
    const float* xvp3 = v_up + (size_t)rc3.y * 384 + u0;
    float2 xa0 = *reinterpret_cast<const float2*>(xvp0);
    float2 xb0 = *reinterpret_cast<const float2*>(xvp0 + 128);
    float2 xc0 = *reinterpret_cast<const float2*>(xvp0 + 256);
    float2 xa1 = *reinterpret_cast<const float2*>(xvp1);
    float2 xb1 = *reinterpret_cast<const float2*>(xvp1 + 128);
    float2 xc1 = *reinterpret_cast<const float2*>(xvp1 + 256);
    float2 xa2 = *reinterpret_cast<const float2*>(xvp2);
    float2 xb2 = *reinterpret_cast<const float2*>(xvp2 + 128);
    float2 xc2 = *reinterpret_cast<const float2*>(xvp2 + 256);
    float2 xa3 = *reinterpret_cast<const float2*>(xvp3);
    float2 xb3 = *reinterpret_cast<const float2*>(xvp3 + 128);
    float2 xc3 = *reinterpret_cast<const float2*>(xvp3 + 256);

    // tail mask via ea (all message terms factor through an ea component)
    const int m = e1 - p0;
    if (m < 4) {
      float k1 = (m > 1) ? 1.f : 0.f;
      float k2 = (m > 2) ? 1.f : 0.f;
      ea1.x *= k1; ea1.y *= k1; ea1.z *= k1; ea1.w *= k1;
      ea2.x *= k2; ea2.y *= k2; ea2.z *= k2; ea2.w *= k2;
      ea3.x = 0.f; ea3.y = 0.f; ea3.z = 0.f; ea3.w = 0.f;
    }

#define ACC_EDGE(EA, QS, QV, XS, XA, XB, XC)                                   \
    {                                                                          \
      float tA0 = __uint_as_float(QS.x << 16);                                 \
      float tB0 = __uint_as_float(QS.x & 0xFFFF0000u);                         \
      float tA1 = __uint_as_float(QS.y << 16);                                 \
      float tB1 = __uint_as_float(QS.y & 0xFFFF0000u);                         \
      aMsS0 += tA0 * XS.x * EA.x;                                              \
      aMsS1 += tA1 * XS.y * EA.x;                                              \
      float wc0 = tB0 * XS.x, wc1 = tB1 * XS.y;                                \
      aVs[0][0] += wc0 * EA.y; aVs[0][1] += wc1 * EA.y;                        \
      aVs[1][0] += wc0 * EA.z; aVs[1][1] += wc1 * EA.z;                        \
      aVs[2][0] += wc0 * EA.w; aVs[2][1] += wc1 * EA.w;                        \
      float uA0 = __uint_as_float(QV.x << 16);                                 \
      float uB0 = __uint_as_float(QV.x & 0xFFFF0000u);                         \
      float uA1 = __uint_as_float(QV.y << 16);                                 \
      float uB1 = __uint_as_float(QV.y & 0xFFFF0000u);                         \
      float dot0 = XA.x * EA.y + XB.x * EA.z + XC.x * EA.w;                    \
      float dot1 = XA.y * EA.y + XB.y * EA.z + XC.y * EA.w;                    \
      aMsV0 += uA0 * dot0 * kINV_SQ3;                                          \
      aMsV1 += uA1 * dot1 * kINV_SQ3;                                          \
      float wd0 = uB0 * EA.x, wd1 = uB1 * EA.x;                                \
      aVv[0][0] += wd0 * XA.x; aVv[0][1] += wd1 * XA.y;                        \
      aVv[1][0] += wd0 * XB.x; aVv[1][1] += wd1 * XB.y;                        \
      aVv[2][0] += wd0 * XC.x; aVv[2][1] += wd1 * XC.y;                        \
    }

    ACC_EDGE(ea0, qs0, qv0, xs0, xa0, xb0, xc0)
    ACC_EDGE(ea1, qs1, qv1, xs1, xa1, xb1, xc1)
    ACC_EDGE(ea2, qs2, qv2, xs2, xa2, xb2, xc2)
    ACC_EDGE(ea3, qs3, qv3, xs3, xa3, xb3, xc3)
#undef ACC_EDGE
  }

  *reinterpret_cast<float2*>(Ms + (size_t)n * 256 + u0)       = make_float2(aMsS0, aMsS1);
  *reinterpret_cast<float2*>(Ms + (size_t)n * 256 + 128 + u0) = make_float2(aMsV0, aMsV1);
#pragma unroll
  for (int i = 0; i < 3; ++i) {
    *reinterpret_cast<float2*>(Mv + (size_t)n * 768 + i * 256 + u0) =
        make_float2(aVs[i][0], aVs[i][1]);
    *reinterpret_cast<float2*>(Mv + (size_t)n * 768 + i * 256 + 128 + u0) =
        make_float2(aVv[i][0], aVv[i][1]);
  }
}

// ---------------------------------------------------------------------------
// K5 (MFMA): fused lin + skip + combine (unchanged — passed).
// ---------------------------------------------------------------------------
__global__ __launch_bounds__(256) void k_linskip(
    const float* __restrict__ Ms, const float* __restrict__ Mv,
    const short* __restrict__ Wl0T, const short* __restrict__ Wl1T,
    const short* __restrict__ Wsk0T, const short* __restrict__ Wsk1T,
    const float* __restrict__ attrs, const float* __restrict__ upd,
    float* __restrict__ out, int N) {
  __shared__ __align__(16) short lsA[4][16][264];
  __shared__ __align__(16) short lsS[4][16][136];
  __shared__ float sat[16][4];
  const int nb = blockIdx.x * 16;
  const int t = threadIdx.x;

  for (int base = t * 4; base < 16 * 1024; base += 1024) {
    int n = base >> 10, j = base & 1023;
    int comp = j >> 8, u = j & 255;
    float4 q = {0.f, 0.f, 0.f, 0.f};
    if (nb + n < N) {
      const float* src = (comp == 0) ? (Ms + (size_t)(nb + n) * 256 + u)
                                     : (Mv + (size_t)(nb + n) * 768 + (size_t)(comp - 1) * 256 + u);
      q = *reinterpret_cast<const float4*>(src);
    }
    lsA[comp][n][u + 0] = f2bf(q.x);
    lsA[comp][n][u + 1] = f2bf(q.y);
    lsA[comp][n][u + 2] = f2bf(q.z);
    lsA[comp][n][u + 3] = f2bf(q.w);
  }
  if (t < 64) {
    int n = t >> 2, v = t & 3;
    sat[n][v] = (nb + n < N) ? attrs[(size_t)(nb + n) * 4 + v] : 0.f;
  }
  __syncthreads();

  const int c = t >> 6;
  const int lane = t & 63;
  const int col = lane & 15;
  const int g = lane >> 4;

  const short* WLT = c ? Wl1T : Wl0T;
  const short* WST = c ? Wsk1T : Wsk0T;

  bf16x8 af1[8];
#pragma unroll
  for (int kk = 0; kk < 8; ++kk)
    af1[kk] = *reinterpret_cast<const bf16x8*>(&lsA[c][col][kk * 32 + g * 8]);

  f32x4 Sreg[8];
#pragma unroll
  for (int nt = 0; nt < 8; ++nt) {
    f32x4 acc = {0.f, 0.f, 0.f, 0.f};
#pragma unroll
    for (int kk = 0; kk < 8; ++kk) {
      bf16x8 bf = *reinterpret_cast<const bf16x8*>(&WLT[(size_t)(nt * 16 + col) * 256 + kk * 32 + g * 8]);
      acc = __builtin_amdgcn_mfma_f32_16x16x32_bf16(af1[kk], bf, acc, 0, 0, 0);
    }
#pragma unroll
    for (int r = 0; r < 4; ++r) acc[r] *= kINV_LIN;
    Sreg[nt] = acc;
#pragma unroll
    for (int r = 0; r < 4; ++r)
      lsS[c][g * 4 + r][nt * 16 + col] = f2bf(acc[r]);
  }

  float satr[4][4];
#pragma unroll
  for (int r = 0; r < 4; ++r)
#pragma unroll
    for (int v = 0; v < 4; ++v) satr[r][v] = sat[g * 4 + r][v];

  __syncthreads();

  bf16x8 af2[4];
#pragma unroll
  for (int kk = 0; kk < 4; ++kk)
    af2[kk] = *reinterpret_cast<const bf16x8*>(&lsS[c][col][kk * 32 + g * 8]);

  const float p = upd[0];
  const float cc = 1.f / (1.f + __expf(-p));
  const float c_old = rsqrtf(cc * cc + 1.f);
  const float c_new = cc * c_old;

#pragma unroll
  for (int nt = 0; nt < 8; ++nt) {
    float fin[4] = {0.f, 0.f, 0.f, 0.f};
#pragma unroll
    for (int v = 0; v < 4; ++v) {
      f32x4 tmp = {0.f, 0.f, 0.f, 0.f};
#pragma unroll
      for (int kk = 0; kk < 4; ++kk) {
        bf16x8 bf = *reinterpret_cast<const bf16x8*>(&WST[(size_t)(nt * 16 + col) * 512 + v * 128 + kk * 32 + g * 8]);
        tmp = __builtin_amdgcn_mfma_f32_16x16x32_bf16(af2[kk], bf, tmp, 0, 0, 0);
      }
#pragma unroll
      for (int r = 0; r < 4; ++r) fin[r] += satr[r][v] * tmp[r];
    }
#pragma unroll
    for (int r = 0; r < 4; ++r) {
      int nd = nb + g * 4 + r;
      if (nd < N) {
        float val = c_old * Sreg[nt][r] + c_new * fin[r] * kINV_SK;
        out[((size_t)nd * 128 + nt * 16 + col) * 4 + c] = val;
      }
    }
  }
}

extern "C" void kernel_launch(void* const* d_in, const int* in_sizes, int n_in,
                              void* d_out, int out_size, void* d_ws, size_t ws_size,
                              hipStream_t stream) {
  const float* node_attrs = (const float*)d_in[0];
  const float* node_feats = (const float*)d_in[1];
  const float* edge_attrs = (const float*)d_in[2];
  const float* edge_feats = (const float*)d_in[3];
  const int*   edge_index = (const int*)d_in[4];
  const float* W_up0  = (const float*)d_in[5];
  const float* W_up1  = (const float*)d_in[6];
  const float* W_mlp1 = (const float*)d_in[7];
  const float* W_mlp2 = (const float*)d_in[8];
  const float* W_mlp3 = (const float*)d_in[9];
  const float* W_lin0 = (const float*)d_in[10];
  const float* W_lin1 = (const float*)d_in[11];
  const float* W_skip0 = (const float*)d_in[12];
  const float* W_skip1 = (const float*)d_in[13];
  const float* upd = (const float*)d_in[14];
  float* out = (float*)d_out;

  const int N = in_sizes[0] / 4;
  const int E = in_sizes[4] / 2;

  float* ws = (float*)d_ws;
  float* s_up = ws;                          // N*128
  float* v_up = s_up + (size_t)N * 128;      // N*384  [n][i][u]
  float* Ms   = v_up + (size_t)N * 384;      // N*256
  float* Mv   = Ms + (size_t)N * 256;        // N*768  [n][i][u]
  int* cnt    = (int*)(Mv + (size_t)N * 768); // N
  int* offs   = cnt + N;                      // N+1
  int* cursor = offs + N + 1;                 // N
  uint2* recs = (uint2*)((((uintptr_t)(cursor + N)) + 7) & ~(uintptr_t)7);  // E uint2

  short* wbase = (short*)((((uintptr_t)(recs + E)) + 15) & ~(uintptr_t)15);
  short* W0T   = wbase;            // 128*128
  short* W1T   = W0T + 16384;      // 128*128
  short* Wl0T  = W1T + 16384;      // 128*256
  short* Wl1T  = Wl0T + 32768;     // 128*256
  short* Wsk0T = Wl1T + 32768;     // 128*512
  short* Wsk1T = Wsk0T + 65536;    // 128*512
  short* W2T   = Wsk1T + 65536;    // 64*64
  short* W3T   = W2T + 4096;       // 512*64
  unsigned* tpw2 = (unsigned*)(W3T + 32768); // E*256 dwords

  const int CVT_B = (266240 + 255) / 256;      // 1040
  const int CNT_B = (E + 255) / 256;
  const int MLP_B = (E + 127) / 128;
  const int UP_B  = (N + 15) / 16;
  const int SC_B  = (E + 255) / 256;

  hipMemsetAsync(cnt, 0, (size_t)N * sizeof(int), stream);

  k_cvtcnt<<<CVT_B + CNT_B, 256, 0, stream>>>(
      W_up0, W_up1, W_lin0, W_lin1, W_skip0, W_skip1, W_mlp2, W_mlp3,
      W0T, W1T, Wl0T, Wl1T, Wsk0T, Wsk1T, W2T, W3T,
      edge_index, cnt, E, CVT_B);
  k_scan<<<1, 1024, 0, stream>>>(cnt, offs, cursor, N);
  k_fused3<<<MLP_B + UP_B + SC_B, 256, 0, stream>>>(
      edge_index, cursor, recs,
      node_feats, W0T, W1T, s_up, v_up,
      edge_feats, W_mlp1, W2T, W3T, tpw2, N, E, MLP_B, UP_B);
  k_gather<<<(N + 3) / 4, 256, 0, stream>>>(recs, offs, tpw2, edge_attrs,
                                            s_up, v_up, Ms, Mv, N);
  k_linskip<<<(N + 15) / 16, 256, 0, stream>>>(Ms, Mv, Wl0T, Wl1T, Wsk0T, Wsk1T,
                                               node_attrs, upd, out, N);
}